// Round 1
// 884.571 us; speedup vs baseline: 1.8813x; 1.8813x over previous
//
#include <hip/hip_runtime.h>

// Problem constants
#define B_ 64
#define S_ 1024
#define D_ 512
#define F_ 256
#define H_ 512

// ws word-offset layout (fp32 words) — identical 622,612-word footprint as before.
// Overlays (stream-ordered, no races):
//   WPEL (WpE-lo)  = old sc_em+sc_fm region; consumed by score_mfma_split<512>,
//                    then first 256 words reused as CHK (subset ground truth).
//   WPFL (WpF-lo)  = gammas region; consumed by score_mfma_split<256> BEFORE
//                    softmax overwrites it with gammas.
#define FLAGS_W  0
#define ST_F_W   16
#define ST_X_W   32784
#define SC_E_W   65552
#define SC_F_W   131088
#define WPEL_W   196624
#define CHK_W    196624
#define WPFL_W   327696
#define GAM_W    327696
#define CTX_W    393232
#define WPEH_W   426000
#define WPFH_W   557072
#define CANARY_W 622608
// total: 622612 words = 2,490,448 bytes

typedef __attribute__((ext_vector_type(8))) short bf16x8;
typedef __attribute__((ext_vector_type(4))) short bf16x4;
typedef __attribute__((ext_vector_type(4))) float f32x4;
typedef unsigned short u16;
typedef unsigned int u32;

__device__ inline float bf2f(u16 u) {
  u32 i = ((u32)u) << 16;
  float f;
  __builtin_memcpy(&f, &i, 4);
  return f;
}
__device__ inline u16 f2bf(float f) {
  u32 i;
  __builtin_memcpy(&i, &f, 4);
  u32 r = i + 0x7fffu + ((i >> 16) & 1u);  // RNE
  return (u16)(r >> 16);
}
// Dual-mode input load: f32 flag selects fp32 or bf16 interpretation.
__device__ inline float ldin(const void* p, size_t i, int f32) {
  return f32 ? ((const float*)p)[i] : bf2f(((const u16*)p)[i]);
}
__device__ inline void stout(void* p, size_t i, float v, int f32) {
  if (f32) ((float*)p)[i] = v;
  else ((u16*)p)[i] = f2bf(v);
}
__device__ inline float fast_tanh(float x) {
  float cx = fminf(15.f, fmaxf(-15.f, x));
  float e = __expf(2.f * cx);
  return (e - 1.f) * __builtin_amdgcn_rcpf(e + 1.f);
}

// ---------------------------------------------------------------------------
// Dtype probe on W_e raw u16s + flags/canary init.
__global__ void probe_kernel(const u16* __restrict__ We, u32* __restrict__ flags,
                             u32* __restrict__ canary) {
  __shared__ u32 cnt;
  if (threadIdx.x == 0) cnt = 0;
  __syncthreads();
  u32 local = 0;
  for (int i = threadIdx.x; i < 65536; i += 256) {
    u32 e = (We[i] >> 7) & 0xFF;  // bf16 exponent field
    if (e >= 134) ++local;        // |v| >= 128: impossible for bf16 N(0,1)*0.044 data
  }
  atomicAdd(&cnt, local);
  __syncthreads();
  if (threadIdx.x == 0) {
    flags[0] = (cnt > 1000) ? 1u : 0u;  // 1 => inputs are fp32
    for (int i = 1; i < 16; ++i) flags[i] = 0;
    canary[0] = 0xC0DE0001u; canary[1] = 0xC0DE0002u;
    canary[2] = 0xC0DE0003u; canary[3] = 0xC0DE0004u;
  }
}

__global__ void zero_kernel(float* __restrict__ p, int n) {
  int i = blockIdx.x * blockDim.x + threadIdx.x;
  if (i < n) p[i] = 0.f;
}

// ---------------------------------------------------------------------------
__global__ void state_kernel(const void* __restrict__ x,
                             const void* __restrict__ Wsf, const void* __restrict__ bsf,
                             const void* __restrict__ Wse, const void* __restrict__ bse,
                             float* __restrict__ st_f, float* __restrict__ st_x,
                             const u32* __restrict__ flags) {
  const int f32 = flags[0];
  int tid = blockIdx.x * 256 + threadIdx.x;
  int h = tid & 511, b = (tid >> 9) & 63, which = tid >> 15;
  const void* W = which ? Wse : Wsf;
  const void* bias = which ? bse : bsf;
  float a0 = 0.f, a1 = 0.f, a2 = 0.f, a3 = 0.f;
  for (int d = 0; d < D_; d += 4) {
    a0 += ldin(x, b * D_ + d, f32)     * ldin(W, (size_t)d * H_ + h, f32);
    a1 += ldin(x, b * D_ + d + 1, f32) * ldin(W, (size_t)(d + 1) * H_ + h, f32);
    a2 += ldin(x, b * D_ + d + 2, f32) * ldin(W, (size_t)(d + 2) * H_ + h, f32);
    a3 += ldin(x, b * D_ + d + 3, f32) * ldin(W, (size_t)(d + 3) * H_ + h, f32);
  }
  float acc = (a0 + a1) + (a2 + a3);
  float v = fast_tanh(acc + ldin(bias, h, f32));
  (which ? st_x : st_f)[b * H_ + h] = v;
}

// ---------------------------------------------------------------------------
// Scalar score path — now used only as a SUBSET ground-truth check (16 blocks).
template <int K>
__global__ void score_scalar(const void* __restrict__ A, const void* __restrict__ W,
                             const void* __restrict__ bias, const float* __restrict__ st,
                             float* __restrict__ score, const u32* __restrict__ flags) {
  __shared__ float Af[16 * K];
  __shared__ float part[4][16];
  const int f32 = flags[0];
  const int tid = threadIdx.x;
  const int m0 = blockIdx.x * 16;
  const int b = m0 >> 10, sb = m0 & 1023;
  for (int g = tid; g < 16 * K; g += 256) Af[g] = ldin(A, (size_t)m0 * K + g, f32);
  __syncthreads();
  const int h0 = tid * 2, h1 = h0 + 1;
  float acc0[16], acc1[16];
#pragma unroll
  for (int r = 0; r < 16; ++r) acc0[r] = acc1[r] = 0.f;
  for (int k = 0; k < K; k += 2) {
    float w00 = ldin(W, (size_t)k * H_ + h0, f32), w01 = ldin(W, (size_t)k * H_ + h1, f32);
    float w10 = ldin(W, (size_t)(k + 1) * H_ + h0, f32), w11 = ldin(W, (size_t)(k + 1) * H_ + h1, f32);
#pragma unroll
    for (int r = 0; r < 16; ++r) {
      float ax = Af[r * K + k], ay = Af[r * K + k + 1];
      acc0[r] += ax * w00;
      acc0[r] += ay * w10;
      acc1[r] += ax * w01;
      acc1[r] += ay * w11;
    }
  }
  const float s0v = st[b * H_ + h0], s1v = st[b * H_ + h1];
  const float bi0 = ldin(bias, h0, f32), bi1 = ldin(bias, h1, f32);
  const int lane = tid & 63, wave = tid >> 6;
  for (int r = 0; r < 16; ++r) {
    float p = fast_tanh(acc0[r] + bi0) * s0v + fast_tanh(acc1[r] + bi1) * s1v;
    p += __shfl_xor(p, 1);
    p += __shfl_xor(p, 2);
    p += __shfl_xor(p, 4);
    p += __shfl_xor(p, 8);
    p += __shfl_xor(p, 16);
    p += __shfl_xor(p, 32);
    if (lane == 0) part[wave][r] = p;
  }
  __syncthreads();
  if (tid < 16)
    score[b * S_ + sb + tid] = part[0][tid] + part[1][tid] + part[2][tid] + part[3][tid];
}

// ---------------------------------------------------------------------------
// W pack with hi/lo bf16 split (dual-mode input; lo == 0 exactly in bf16 mode).
// Tile (kc,nc): 32 k x 16 n; lane holds 8 k-values (k=(lane>>4)*8+j) of column
// nb = nc*16 + (lane&15) — matches the MFMA B-fragment layout.
__global__ void pack_w_split(const void* __restrict__ W, u16* __restrict__ WpH,
                             u16* __restrict__ WpL, int K, const u32* __restrict__ flags) {
  const int f32 = flags[0];
  int t = blockIdx.x * blockDim.x + threadIdx.x;
  int lane = t & 63, tile = t >> 6;
  if (tile >= (K >> 5) * 32) return;
  int kc = tile >> 5, nc = tile & 31;
  int kb = kc * 32 + ((lane >> 4) << 3);
  int nb = nc * 16 + (lane & 15);
  u16 vh[8], vl[8];
#pragma unroll
  for (int j = 0; j < 8; ++j) {
    float v = ldin(W, (size_t)(kb + j) * H_ + nb, f32);
    u16 h = f2bf(v);
    vh[j] = h;
    vl[j] = f2bf(v - bf2f(h));
  }
  size_t off = ((size_t)tile << 9) + (size_t)lane * 8;
#pragma unroll
  for (int j = 0; j < 8; ++j) {
    WpH[off + j] = vh[j];
    WpL[off + j] = vl[j];
  }
}

// ---------------------------------------------------------------------------
// CONSUMED score path: split-bf16 3-pass MFMA (Ah*Wh + Al*Wh + Ah*Wl).
// fp32-grade accuracy (lo*lo term ~2^-18 relative), ~3x MFMA work but on the
// 2.4 PF matrix pipe instead of the 157 TF vector pipe.
template <int K>
__global__ void __launch_bounds__(512, 2) score_mfma_split(
    const void* __restrict__ A, const u16* __restrict__ WpH, const u16* __restrict__ WpL,
    const void* __restrict__ bias, const float* __restrict__ st,
    float* __restrict__ score, const u32* __restrict__ flags) {
  constexpr int KP = 128, LDK = KP + 8;
  __shared__ __attribute__((aligned(16))) short AsH[64 * LDK];
  __shared__ __attribute__((aligned(16))) short AsL[64 * LDK];
  __shared__ float scw[8][64];
  const int f32 = flags[0];
  const int tid = threadIdx.x;
  const int m0 = blockIdx.x * 64;
  const int b = m0 >> 10, s0 = m0 & 1023;
  const int lane = tid & 63, wave = tid >> 6;
  const int ml = lane & 15, q = lane >> 4;
  const int nb = wave * 4;
  const bf16x8* wph = (const bf16x8*)WpH;
  const bf16x8* wpl = (const bf16x8*)WpL;
  f32x4 acc[4][4] = {};
  for (int ph = 0; ph < K / KP; ++ph) {
    if (ph) __syncthreads();
    // Stage 64 x 128 A-tile, splitting fp32 -> hi/lo bf16 on the fly.
    // Each element is staged by exactly one block -> no redundant conversion.
    {
      int c = tid;  // 64*(KP/4) = 2048 chunks of 4 elements; 4 per thread
#pragma unroll
      for (int it = 0; it < (64 * (KP / 4)) / 512; ++it, c += 512) {
        int r = c >> 5, cc = c & 31;
        float v[4];
        if (f32) {
          f32x4 x4 = *(const f32x4*)((const float*)A + (size_t)(m0 + r) * K + ph * KP + cc * 4);
          v[0] = x4[0]; v[1] = x4[1]; v[2] = x4[2]; v[3] = x4[3];
        } else {
          bf16x4 x4 = *(const bf16x4*)((const u16*)A + (size_t)(m0 + r) * K + ph * KP + cc * 4);
          v[0] = bf2f((u16)x4[0]); v[1] = bf2f((u16)x4[1]);
          v[2] = bf2f((u16)x4[2]); v[3] = bf2f((u16)x4[3]);
        }
        bf16x4 hv, lv;
#pragma unroll
        for (int j = 0; j < 4; ++j) {
          u16 h = f2bf(v[j]);
          hv[j] = (short)h;
          lv[j] = (short)f2bf(v[j] - bf2f(h));  // exactly 0 in bf16 mode
        }
        *(bf16x4*)&AsH[r * LDK + cc * 4] = hv;
        *(bf16x4*)&AsL[r * LDK + cc * 4] = lv;
      }
    }
    __syncthreads();
    for (int kc = 0; kc < KP / 32; ++kc) {
      const int kcg = ph * (KP / 32) + kc;
      bf16x8 ah[4], al[4], bh[4], bl[4];
#pragma unroll
      for (int ns = 0; ns < 4; ++ns) {
        size_t widx = (size_t)(kcg * 32 + nb + ns) * 64 + lane;
        bh[ns] = wph[widx];
        bl[ns] = wpl[widx];
      }
#pragma unroll
      for (int ms = 0; ms < 4; ++ms) {
        ah[ms] = *(const bf16x8*)&AsH[(ms * 16 + ml) * LDK + kc * 32 + q * 8];
        al[ms] = *(const bf16x8*)&AsL[(ms * 16 + ml) * LDK + kc * 32 + q * 8];
      }
#pragma unroll
      for (int ms = 0; ms < 4; ++ms)
#pragma unroll
        for (int ns = 0; ns < 4; ++ns) {
          acc[ms][ns] = __builtin_amdgcn_mfma_f32_16x16x32_bf16(ah[ms], bh[ns], acc[ms][ns], 0, 0, 0);
          acc[ms][ns] = __builtin_amdgcn_mfma_f32_16x16x32_bf16(al[ms], bh[ns], acc[ms][ns], 0, 0, 0);
          acc[ms][ns] = __builtin_amdgcn_mfma_f32_16x16x32_bf16(ah[ms], bl[ns], acc[ms][ns], 0, 0, 0);
        }
    }
  }
  // Epilogue: tanh + st-weighted reduce over h. C layout: col=lane&15,
  // row=(lane>>4)*4+reg (m89-verified mapping).
  float biasn[4], stn[4];
#pragma unroll
  for (int ns = 0; ns < 4; ++ns) {
    int n = (nb + ns) * 16 + ml;
    biasn[ns] = ldin(bias, n, f32);
    stn[ns] = st[b * H_ + n];
  }
#pragma unroll
  for (int ms = 0; ms < 4; ++ms) {
#pragma unroll
    for (int r = 0; r < 4; ++r) {
      float p = 0.f;
#pragma unroll
      for (int ns = 0; ns < 4; ++ns)
        p += fast_tanh(acc[ms][ns][r] + biasn[ns]) * stn[ns];
      p += __shfl_xor(p, 1);
      p += __shfl_xor(p, 2);
      p += __shfl_xor(p, 4);
      p += __shfl_xor(p, 8);
      if (ml == 0) scw[wave][ms * 16 + q * 4 + r] = p;
    }
  }
  __syncthreads();
  if (tid < 64) {
    float s = 0.f;
#pragma unroll
    for (int w = 0; w < 8; ++w) s += scw[w][tid];
    score[b * S_ + s0 + tid] = s;
  }
}

// Subset diff (256 values) vs scalar ground truth -> flags[slot]. Both modes.
__global__ void diff_sub(const float* __restrict__ a, const float* __restrict__ c,
                         u32* __restrict__ flags, int slot) {
  int i = threadIdx.x;
  float d = fabsf(a[i] - c[i]);
  atomicMax(&flags[slot], __float_as_uint(d));  // d>=0: bit order == value order
}

// NaN / absurd-magnitude scores => flags[4]
__global__ void check_kernel(const float* __restrict__ a, const float* __restrict__ b,
                             u32* __restrict__ flags) {
  int i = blockIdx.x * 256 + threadIdx.x;
  if (!(fabsf(a[i]) < 1e4f) || !(fabsf(b[i]) < 1e4f)) flags[4] = 1;
}

// ~100us spin, fires ONLY if MFMA-split mismatches scalar ground truth on the
// subset — verdict readable from the rocprof dispatch list.
__global__ void marker_mfma_mismatch(const u32* __restrict__ flags, u32* __restrict__ sink) {
  float de = __uint_as_float(flags[2]);
  if (de > 0.02f) {
    float x = 1.f + threadIdx.x * 1e-7f;
    for (int i = 0; i < 60000; ++i) x = __builtin_fmaf(x, 1.0000001f, 1e-9f);
    if (x > 1e30f) *sink = 1;
  }
}

// Error code -> out[0] ONLY for pipeline-poisoning faults (canary, NaN).
__global__ void diag_kernel(const u32* __restrict__ flags, const u32* __restrict__ canary,
                            void* __restrict__ out) {
  if (threadIdx.x != 0) return;
  int f32 = flags[0];
  u32 code = 0;
  if (canary[0] != 0xC0DE0001u || canary[1] != 0xC0DE0002u ||
      canary[2] != 0xC0DE0003u || canary[3] != 0xC0DE0004u) code += 32;
  if (flags[4]) code += 64;
  if (code) stout(out, 0, (float)code, f32);
}

// ---------------------------------------------------------------------------
__device__ inline float block_reduce_max(float v, float* red, int tid) {
#pragma unroll
  for (int off = 32; off >= 1; off >>= 1) v = fmaxf(v, __shfl_xor(v, off));
  if ((tid & 63) == 0) red[tid >> 6] = v;
  __syncthreads();
  v = fmaxf(fmaxf(red[0], red[1]), fmaxf(red[2], red[3]));
  __syncthreads();
  return v;
}
__device__ inline float block_reduce_sum(float v, float* red, int tid) {
#pragma unroll
  for (int off = 32; off >= 1; off >>= 1) v += __shfl_xor(v, off);
  if ((tid & 63) == 0) red[tid >> 6] = v;
  __syncthreads();
  v = red[0] + red[1] + red[2] + red[3];
  __syncthreads();
  return v;
}

__global__ void softmax_kernel(const float* __restrict__ se, const float* __restrict__ sf,
                               float* __restrict__ gam, void* __restrict__ dout,
                               const u32* __restrict__ flags) {
  __shared__ float red[4];
  const int f32 = flags[0];
  int b = blockIdx.x, t = threadIdx.x;
  float e[4], f[4];
#pragma unroll
  for (int i = 0; i < 4; ++i) {
    e[i] = se[b * S_ + t + 256 * i];
    f[i] = sf[b * S_ + t + 256 * i];
  }
  float me = block_reduce_max(fmaxf(fmaxf(e[0], e[1]), fmaxf(e[2], e[3])), red, t);
  float mf = block_reduce_max(fmaxf(fmaxf(f[0], f[1]), fmaxf(f[2], f[3])), red, t);
  float sume = 0.f, sumf = 0.f;
#pragma unroll
  for (int i = 0; i < 4; ++i) {
    e[i] = __expf(e[i] - me);
    sume += e[i];
    f[i] = __expf(f[i] - mf);
    sumf += f[i];
  }
  sume = block_reduce_sum(sume, red, t);
  sumf = block_reduce_sum(sumf, red, t);
  float g[4], tot = 0.f;
#pragma unroll
  for (int i = 0; i < 4; ++i) {
    g[i] = (e[i] / sume) * (f[i] / sumf);
    tot += g[i];
  }
  tot = block_reduce_sum(tot, red, t);
  float scale = 1.f / (1e-6f + tot);
#pragma unroll
  for (int i = 0; i < 4; ++i) {
    int s = t + 256 * i;
    float gv = g[i] * scale;
    gam[b * S_ + s] = gv;
    stout(dout, (size_t)B_ * H_ + (size_t)s * B_ + b, gv, f32);  // gammas [S,B]
  }
}

// ---------------------------------------------------------------------------
__global__ void ctx_kernel(const float* __restrict__ gam, const void* __restrict__ enc,
                           float* __restrict__ ctx, const u32* __restrict__ flags) {
  const int f32 = flags[0];
  int b = blockIdx.x >> 4, sc = blockIdx.x & 15;
  int t = threadIdx.x, d0 = t * 2;
  float a0 = 0.f, a1 = 0.f;
  for (int s = sc * 64; s < sc * 64 + 64; ++s) {
    float g = gam[b * S_ + s];
    size_t base = ((size_t)(b * S_ + s)) * D_ + d0;
    a0 += g * ldin(enc, base, f32);
    a1 += g * ldin(enc, base + 1, f32);
  }
  atomicAdd(&ctx[b * D_ + d0], a0);
  atomicAdd(&ctx[b * D_ + d0 + 1], a1);
}

// ---------------------------------------------------------------------------
__global__ void out_kernel(const float* __restrict__ ctx, const void* __restrict__ x,
                           const void* __restrict__ Wg, const void* __restrict__ bg,
                           void* __restrict__ dout, const u32* __restrict__ flags) {
  const int f32 = flags[0];
  int tid = blockIdx.x * 256 + threadIdx.x;
  int h = tid & 511, b = tid >> 9;
  float a0 = 0.f, a1 = 0.f, a2 = 0.f, a3 = 0.f;
  for (int d = 0; d < D_; d += 4) {
    a0 += ctx[b * D_ + d]     * ldin(Wg, (size_t)d * H_ + h, f32);
    a1 += ctx[b * D_ + d + 1] * ldin(Wg, (size_t)(d + 1) * H_ + h, f32);
    a2 += ctx[b * D_ + d + 2] * ldin(Wg, (size_t)(d + 2) * H_ + h, f32);
    a3 += ctx[b * D_ + d + 3] * ldin(Wg, (size_t)(d + 3) * H_ + h, f32);
  }
  for (int d = 0; d < D_; d += 4) {
    a0 += ldin(x, b * D_ + d, f32)     * ldin(Wg, (size_t)(D_ + d) * H_ + h, f32);
    a1 += ldin(x, b * D_ + d + 1, f32) * ldin(Wg, (size_t)(D_ + d + 1) * H_ + h, f32);
    a2 += ldin(x, b * D_ + d + 2, f32) * ldin(Wg, (size_t)(D_ + d + 2) * H_ + h, f32);
    a3 += ldin(x, b * D_ + d + 3, f32) * ldin(Wg, (size_t)(D_ + d + 3) * H_ + h, f32);
  }
  float acc = (a0 + a1) + (a2 + a3);
  stout(dout, (size_t)b * H_ + h, fast_tanh(acc + ldin(bg, h, f32)), f32);
}

// ---------------------------------------------------------------------------
extern "C" void kernel_launch(void* const* d_in, const int* in_sizes, int n_in,
                              void* d_out, int out_size, void* d_ws, size_t ws_size,
                              hipStream_t stream) {
  const void* x    = d_in[0];
  const void* enc  = d_in[1];
  const void* fld  = d_in[2];
  const void* W_f  = d_in[3];
  const void* b_f  = d_in[4];
  const void* W_e  = d_in[5];
  const void* b_e  = d_in[6];
  const void* W_sf = d_in[7];
  const void* b_sf = d_in[8];
  const void* W_se = d_in[9];
  const void* b_se = d_in[10];
  const void* W_g  = d_in[11];
  const void* b_g  = d_in[12];

  float* ws    = (float*)d_ws;
  u32* flags   = (u32*)(ws + FLAGS_W);
  float* st_f  = ws + ST_F_W;
  float* st_x  = ws + ST_X_W;
  float* sc_e  = ws + SC_E_W;
  float* sc_f  = ws + SC_F_W;
  float* gam   = ws + GAM_W;
  float* ctx   = ws + CTX_W;
  float* chk   = ws + CHK_W;
  u16* WpEH    = (u16*)(ws + WPEH_W);
  u16* WpEL    = (u16*)(ws + WPEL_W);
  u16* WpFH    = (u16*)(ws + WPFH_W);
  u16* WpFL    = (u16*)(ws + WPFL_W);
  u32* canary  = (u32*)(ws + CANARY_W);

  probe_kernel<<<1, 256, 0, stream>>>((const u16*)W_e, flags, canary);
  zero_kernel<<<32, 1024, 0, stream>>>(ctx, B_ * D_);
  state_kernel<<<256, 256, 0, stream>>>(x, W_sf, b_sf, W_se, b_se, st_f, st_x, flags);
  pack_w_split<<<128, 256, 0, stream>>>(W_e, WpEH, WpEL, 512, flags);
  pack_w_split<<<64, 256, 0, stream>>>(W_f, WpFH, WpFL, 256, flags);
  score_mfma_split<512><<<1024, 512, 0, stream>>>(enc, WpEH, WpEL, b_e, st_x, sc_e, flags);
  score_mfma_split<256><<<1024, 512, 0, stream>>>(fld, WpFH, WpFL, b_f, st_f, sc_f, flags);
  // Ground-truth subset check: rows 0..255 of the enc score via the scalar path.
  score_scalar<512><<<16, 256, 0, stream>>>(enc, W_e, b_e, st_x, chk, flags);
  diff_sub<<<1, 256, 0, stream>>>(chk, sc_e, flags, 2);
  check_kernel<<<256, 256, 0, stream>>>(sc_e, sc_f, flags);
  marker_mfma_mismatch<<<1, 64, 0, stream>>>(flags, &flags[15]);
  softmax_kernel<<<64, 256, 0, stream>>>(sc_e, sc_f, gam, d_out, flags);
  ctx_kernel<<<1024, 256, 0, stream>>>(gam, enc, ctx, flags);
  out_kernel<<<128, 256, 0, stream>>>(ctx, x, W_g, b_g, d_out, flags);
  diag_kernel<<<1, 64, 0, stream>>>(flags, canary, d_out);
}

// Round 2
// 668.039 us; speedup vs baseline: 2.4911x; 1.3241x over previous
//
#include <hip/hip_runtime.h>

// Problem constants
#define B_ 64
#define S_ 1024
#define D_ 512
#define F_ 256
#define H_ 512

// ws word-offset layout (fp32 words) — identical 622,612-word footprint.
// Overlays (stream-ordered, no races):
//   WPEL (WpE-lo) = old sc_em/sc_fm region; consumed by score_mfma_split<512>.
//   WPFL (WpF-lo) = gammas region; consumed by score_mfma_split<256> BEFORE
//                   softmax overwrites it with gammas.
#define FLAGS_W  0
#define ST_F_W   16
#define ST_X_W   32784
#define SC_E_W   65552
#define SC_F_W   131088
#define WPEL_W   196624
#define WPFL_W   327696
#define GAM_W    327696
#define CTX_W    393232
#define WPEH_W   426000
#define WPFH_W   557072
#define CANARY_W 622608
// total: 622612 words = 2,490,448 bytes

typedef __attribute__((ext_vector_type(8))) short bf16x8;
typedef __attribute__((ext_vector_type(4))) short bf16x4;
typedef __attribute__((ext_vector_type(4))) float f32x4;
typedef unsigned short u16;
typedef unsigned int u32;

__device__ inline float bf2f(u16 u) {
  u32 i = ((u32)u) << 16;
  float f;
  __builtin_memcpy(&f, &i, 4);
  return f;
}
__device__ inline u16 f2bf(float f) {
  u32 i;
  __builtin_memcpy(&i, &f, 4);
  u32 r = i + 0x7fffu + ((i >> 16) & 1u);  // RNE
  return (u16)(r >> 16);
}
// Dual-mode input load: f32 flag selects fp32 or bf16 interpretation.
__device__ inline float ldin(const void* p, size_t i, int f32) {
  return f32 ? ((const float*)p)[i] : bf2f(((const u16*)p)[i]);
}
__device__ inline void stout(void* p, size_t i, float v, int f32) {
  if (f32) ((float*)p)[i] = v;
  else ((u16*)p)[i] = f2bf(v);
}
__device__ inline float fast_tanh(float x) {
  float cx = fminf(15.f, fmaxf(-15.f, x));
  float e = __expf(2.f * cx);
  return (e - 1.f) * __builtin_amdgcn_rcpf(e + 1.f);
}

// ---------------------------------------------------------------------------
// Dtype probe on W_e raw u16s + flags/canary init.
__global__ void probe_kernel(const u16* __restrict__ We, u32* __restrict__ flags,
                             u32* __restrict__ canary) {
  __shared__ u32 cnt;
  if (threadIdx.x == 0) cnt = 0;
  __syncthreads();
  u32 local = 0;
  for (int i = threadIdx.x; i < 65536; i += 256) {
    u32 e = (We[i] >> 7) & 0xFF;  // bf16 exponent field
    if (e >= 134) ++local;        // |v| >= 128: impossible for bf16 N(0,1)*0.044 data
  }
  atomicAdd(&cnt, local);
  __syncthreads();
  if (threadIdx.x == 0) {
    flags[0] = (cnt > 1000) ? 1u : 0u;  // 1 => inputs are fp32
    for (int i = 1; i < 16; ++i) flags[i] = 0;
    canary[0] = 0xC0DE0001u; canary[1] = 0xC0DE0002u;
    canary[2] = 0xC0DE0003u; canary[3] = 0xC0DE0004u;
  }
}

__global__ void zero_kernel(float* __restrict__ p, int n) {
  int i = blockIdx.x * blockDim.x + threadIdx.x;
  if (i < n) p[i] = 0.f;
}

// ---------------------------------------------------------------------------
__global__ void state_kernel(const void* __restrict__ x,
                             const void* __restrict__ Wsf, const void* __restrict__ bsf,
                             const void* __restrict__ Wse, const void* __restrict__ bse,
                             float* __restrict__ st_f, float* __restrict__ st_x,
                             const u32* __restrict__ flags) {
  const int f32 = flags[0];
  int tid = blockIdx.x * 256 + threadIdx.x;
  int h = tid & 511, b = (tid >> 9) & 63, which = tid >> 15;
  const void* W = which ? Wse : Wsf;
  const void* bias = which ? bse : bsf;
  float a0 = 0.f, a1 = 0.f, a2 = 0.f, a3 = 0.f;
  for (int d = 0; d < D_; d += 4) {
    a0 += ldin(x, b * D_ + d, f32)     * ldin(W, (size_t)d * H_ + h, f32);
    a1 += ldin(x, b * D_ + d + 1, f32) * ldin(W, (size_t)(d + 1) * H_ + h, f32);
    a2 += ldin(x, b * D_ + d + 2, f32) * ldin(W, (size_t)(d + 2) * H_ + h, f32);
    a3 += ldin(x, b * D_ + d + 3, f32) * ldin(W, (size_t)(d + 3) * H_ + h, f32);
  }
  float acc = (a0 + a1) + (a2 + a3);
  float v = fast_tanh(acc + ldin(bias, h, f32));
  (which ? st_x : st_f)[b * H_ + h] = v;
}

// ---------------------------------------------------------------------------
// W pack with hi/lo bf16 split (dual-mode input; lo == 0 exactly in bf16 mode).
// Tile (kc,nc): 32 k x 16 n; lane holds 8 k-values (k=(lane>>4)*8+j) of column
// nb = nc*16 + (lane&15) — matches the MFMA B-fragment layout.
__global__ void pack_w_split(const void* __restrict__ W, u16* __restrict__ WpH,
                             u16* __restrict__ WpL, int K, const u32* __restrict__ flags) {
  const int f32 = flags[0];
  int t = blockIdx.x * blockDim.x + threadIdx.x;
  int lane = t & 63, tile = t >> 6;
  if (tile >= (K >> 5) * 32) return;
  int kc = tile >> 5, nc = tile & 31;
  int kb = kc * 32 + ((lane >> 4) << 3);
  int nb = nc * 16 + (lane & 15);
  u16 vh[8], vl[8];
#pragma unroll
  for (int j = 0; j < 8; ++j) {
    float v = ldin(W, (size_t)(kb + j) * H_ + nb, f32);
    u16 h = f2bf(v);
    vh[j] = h;
    vl[j] = f2bf(v - bf2f(h));
  }
  size_t off = ((size_t)tile << 9) + (size_t)lane * 8;
#pragma unroll
  for (int j = 0; j < 8; ++j) {
    WpH[off + j] = vh[j];
    WpL[off + j] = vl[j];
  }
}

// ---------------------------------------------------------------------------
// CONSUMED score path: split-bf16 3-pass MFMA (Ah*Wh + Al*Wh + Ah*Wl).
// fp32-grade accuracy (dropped lo*lo term ~2^-18 relative).
// T14 async-STAGE: issue phase p+1 global loads BEFORE computing phase p;
// convert+ds_write after the end-of-compute barrier (HBM latency hides under
// MFMA). T5 setprio around the MFMA cluster (loader/MFMA wave role split).
template <int K>
__global__ void __launch_bounds__(512, 2) score_mfma_split(
    const void* __restrict__ A, const u16* __restrict__ WpH, const u16* __restrict__ WpL,
    const void* __restrict__ bias, const float* __restrict__ st,
    float* __restrict__ score, const u32* __restrict__ flags) {
  constexpr int KP = 128, LDK = KP + 8, NPH = K / KP;
  __shared__ __attribute__((aligned(16))) short AsH[64 * LDK];
  __shared__ __attribute__((aligned(16))) short AsL[64 * LDK];
  __shared__ float scw[8][64];
  const int f32 = flags[0];
  const int tid = threadIdx.x;
  const int m0 = blockIdx.x * 64;
  const int b = m0 >> 10, s0 = m0 & 1023;
  const int lane = tid & 63, wave = tid >> 6;
  const int ml = lane & 15, q = lane >> 4;
  const int nb = wave * 4;
  const bf16x8* wph = (const bf16x8*)WpH;
  const bf16x8* wpl = (const bf16x8*)WpL;
  // Per-thread staging slice: 4 chunks of 4 elems; chunk it -> row (tid>>5)+16*it,
  // col-chunk (tid&31). Coalesced: lanes cover 512B-contiguous row segments.
  const int sr = tid >> 5, scc = tid & 31;
  f32x4 pre[4];   // fp32-mode prefetch
  bf16x4 preb[4]; // bf16-mode prefetch

#define ISSUE_LOADS(PH)                                                              \
  do {                                                                               \
    if (f32) {                                                                       \
      _Pragma("unroll") for (int it = 0; it < 4; ++it)                               \
          pre[it] = *(const f32x4*)((const float*)A +                                \
                                    (size_t)(m0 + sr + 16 * it) * K + (PH)*KP + scc * 4); \
    } else {                                                                         \
      _Pragma("unroll") for (int it = 0; it < 4; ++it)                               \
          preb[it] = *(const bf16x4*)((const u16*)A +                                \
                                      (size_t)(m0 + sr + 16 * it) * K + (PH)*KP + scc * 4); \
    }                                                                                \
  } while (0)

#define WRITE_STAGE()                                                                \
  do {                                                                               \
    _Pragma("unroll") for (int it = 0; it < 4; ++it) {                               \
      float v[4];                                                                    \
      if (f32) {                                                                     \
        v[0] = pre[it][0]; v[1] = pre[it][1]; v[2] = pre[it][2]; v[3] = pre[it][3];  \
      } else {                                                                       \
        v[0] = bf2f((u16)preb[it][0]); v[1] = bf2f((u16)preb[it][1]);                \
        v[2] = bf2f((u16)preb[it][2]); v[3] = bf2f((u16)preb[it][3]);                \
      }                                                                              \
      bf16x4 hv, lv;                                                                 \
      _Pragma("unroll") for (int j = 0; j < 4; ++j) {                                \
        u16 h = f2bf(v[j]);                                                          \
        hv[j] = (short)h;                                                            \
        lv[j] = (short)f2bf(v[j] - bf2f(h));                                         \
      }                                                                              \
      *(bf16x4*)&AsH[(sr + 16 * it) * LDK + scc * 4] = hv;                           \
      *(bf16x4*)&AsL[(sr + 16 * it) * LDK + scc * 4] = lv;                           \
    }                                                                                \
  } while (0)

  f32x4 acc[4][4] = {};
  // Prologue: stage phase 0.
  ISSUE_LOADS(0);
  WRITE_STAGE();
  __syncthreads();
  for (int ph = 0; ph < NPH; ++ph) {
    if (ph + 1 < NPH) ISSUE_LOADS(ph + 1);  // in flight across the compute phase
    for (int kc = 0; kc < KP / 32; ++kc) {
      const int kcg = ph * (KP / 32) + kc;
      bf16x8 ah[4], al[4], bh[4], bl[4];
#pragma unroll
      for (int ns = 0; ns < 4; ++ns) {
        size_t widx = (size_t)(kcg * 32 + nb + ns) * 64 + lane;
        bh[ns] = wph[widx];
        bl[ns] = wpl[widx];
      }
#pragma unroll
      for (int ms = 0; ms < 4; ++ms) {
        ah[ms] = *(const bf16x8*)&AsH[(ms * 16 + ml) * LDK + kc * 32 + q * 8];
        al[ms] = *(const bf16x8*)&AsL[(ms * 16 + ml) * LDK + kc * 32 + q * 8];
      }
      __builtin_amdgcn_s_setprio(1);
#pragma unroll
      for (int ms = 0; ms < 4; ++ms)
#pragma unroll
        for (int ns = 0; ns < 4; ++ns) {
          acc[ms][ns] = __builtin_amdgcn_mfma_f32_16x16x32_bf16(ah[ms], bh[ns], acc[ms][ns], 0, 0, 0);
          acc[ms][ns] = __builtin_amdgcn_mfma_f32_16x16x32_bf16(al[ms], bh[ns], acc[ms][ns], 0, 0, 0);
          acc[ms][ns] = __builtin_amdgcn_mfma_f32_16x16x32_bf16(ah[ms], bl[ns], acc[ms][ns], 0, 0, 0);
        }
      __builtin_amdgcn_s_setprio(0);
    }
    if (ph + 1 < NPH) {
      __syncthreads();   // all reads of As done
      WRITE_STAGE();     // compiler inserts vmcnt before pre[] use
      __syncthreads();   // As ready for next phase
    }
  }
  // Epilogue: tanh + st-weighted reduce over h. C layout: col=lane&15,
  // row=(lane>>4)*4+reg (m89-verified mapping).
  float biasn[4], stn[4];
#pragma unroll
  for (int ns = 0; ns < 4; ++ns) {
    int n = (nb + ns) * 16 + ml;
    biasn[ns] = ldin(bias, n, f32);
    stn[ns] = st[b * H_ + n];
  }
#pragma unroll
  for (int ms = 0; ms < 4; ++ms) {
#pragma unroll
    for (int r = 0; r < 4; ++r) {
      float p = 0.f;
#pragma unroll
      for (int ns = 0; ns < 4; ++ns)
        p += fast_tanh(acc[ms][ns][r] + biasn[ns]) * stn[ns];
      p += __shfl_xor(p, 1);
      p += __shfl_xor(p, 2);
      p += __shfl_xor(p, 4);
      p += __shfl_xor(p, 8);
      if (ml == 0) scw[wave][ms * 16 + q * 4 + r] = p;
    }
  }
  __syncthreads();
  if (tid < 64) {
    float s = 0.f;
#pragma unroll
    for (int w = 0; w < 8; ++w) s += scw[w][tid];
    score[b * S_ + s0 + tid] = s;
  }
#undef ISSUE_LOADS
#undef WRITE_STAGE
}

// NaN / absurd-magnitude scores => flags[4]
__global__ void check_kernel(const float* __restrict__ a, const float* __restrict__ b,
                             u32* __restrict__ flags) {
  int i = blockIdx.x * 256 + threadIdx.x;
  if (!(fabsf(a[i]) < 1e4f) || !(fabsf(b[i]) < 1e4f)) flags[4] = 1;
}

// Error code -> out[0] ONLY for pipeline-poisoning faults (canary, NaN).
__global__ void diag_kernel(const u32* __restrict__ flags, const u32* __restrict__ canary,
                            void* __restrict__ out) {
  if (threadIdx.x != 0) return;
  int f32 = flags[0];
  u32 code = 0;
  if (canary[0] != 0xC0DE0001u || canary[1] != 0xC0DE0002u ||
      canary[2] != 0xC0DE0003u || canary[3] != 0xC0DE0004u) code += 32;
  if (flags[4]) code += 64;
  if (code) stout(out, 0, (float)code, f32);
}

// ---------------------------------------------------------------------------
__device__ inline float block_reduce_max(float v, float* red, int tid) {
#pragma unroll
  for (int off = 32; off >= 1; off >>= 1) v = fmaxf(v, __shfl_xor(v, off));
  if ((tid & 63) == 0) red[tid >> 6] = v;
  __syncthreads();
  v = fmaxf(fmaxf(red[0], red[1]), fmaxf(red[2], red[3]));
  __syncthreads();
  return v;
}
__device__ inline float block_reduce_sum(float v, float* red, int tid) {
#pragma unroll
  for (int off = 32; off >= 1; off >>= 1) v += __shfl_xor(v, off);
  if ((tid & 63) == 0) red[tid >> 6] = v;
  __syncthreads();
  v = red[0] + red[1] + red[2] + red[3];
  __syncthreads();
  return v;
}

__global__ void softmax_kernel(const float* __restrict__ se, const float* __restrict__ sf,
                               float* __restrict__ gam, void* __restrict__ dout,
                               const u32* __restrict__ flags) {
  __shared__ float red[4];
  const int f32 = flags[0];
  int b = blockIdx.x, t = threadIdx.x;
  float e[4], f[4];
#pragma unroll
  for (int i = 0; i < 4; ++i) {
    e[i] = se[b * S_ + t + 256 * i];
    f[i] = sf[b * S_ + t + 256 * i];
  }
  float me = block_reduce_max(fmaxf(fmaxf(e[0], e[1]), fmaxf(e[2], e[3])), red, t);
  float mf = block_reduce_max(fmaxf(fmaxf(f[0], f[1]), fmaxf(f[2], f[3])), red, t);
  float sume = 0.f, sumf = 0.f;
#pragma unroll
  for (int i = 0; i < 4; ++i) {
    e[i] = __expf(e[i] - me);
    sume += e[i];
    f[i] = __expf(f[i] - mf);
    sumf += f[i];
  }
  sume = block_reduce_sum(sume, red, t);
  sumf = block_reduce_sum(sumf, red, t);
  float g[4], tot = 0.f;
#pragma unroll
  for (int i = 0; i < 4; ++i) {
    g[i] = (e[i] / sume) * (f[i] / sumf);
    tot += g[i];
  }
  tot = block_reduce_sum(tot, red, t);
  float scale = 1.f / (1e-6f + tot);
#pragma unroll
  for (int i = 0; i < 4; ++i) {
    int s = t + 256 * i;
    float gv = g[i] * scale;
    gam[b * S_ + s] = gv;
    stout(dout, (size_t)B_ * H_ + (size_t)s * B_ + b, gv, f32);  // gammas [S,B]
  }
}

// ---------------------------------------------------------------------------
__global__ void ctx_kernel(const float* __restrict__ gam, const void* __restrict__ enc,
                           float* __restrict__ ctx, const u32* __restrict__ flags) {
  const int f32 = flags[0];
  int b = blockIdx.x >> 4, sc = blockIdx.x & 15;
  int t = threadIdx.x, d0 = t * 2;
  float a0 = 0.f, a1 = 0.f;
  for (int s = sc * 64; s < sc * 64 + 64; ++s) {
    float g = gam[b * S_ + s];
    size_t base = ((size_t)(b * S_ + s)) * D_ + d0;
    a0 += g * ldin(enc, base, f32);
    a1 += g * ldin(enc, base + 1, f32);
  }
  atomicAdd(&ctx[b * D_ + d0], a0);
  atomicAdd(&ctx[b * D_ + d0 + 1], a1);
}

// ---------------------------------------------------------------------------
__global__ void out_kernel(const float* __restrict__ ctx, const void* __restrict__ x,
                           const void* __restrict__ Wg, const void* __restrict__ bg,
                           void* __restrict__ dout, const u32* __restrict__ flags) {
  const int f32 = flags[0];
  int tid = blockIdx.x * 256 + threadIdx.x;
  int h = tid & 511, b = tid >> 9;
  float a0 = 0.f, a1 = 0.f, a2 = 0.f, a3 = 0.f;
  for (int d = 0; d < D_; d += 4) {
    a0 += ctx[b * D_ + d]     * ldin(Wg, (size_t)d * H_ + h, f32);
    a1 += ctx[b * D_ + d + 1] * ldin(Wg, (size_t)(d + 1) * H_ + h, f32);
    a2 += ctx[b * D_ + d + 2] * ldin(Wg, (size_t)(d + 2) * H_ + h, f32);
    a3 += ctx[b * D_ + d + 3] * ldin(Wg, (size_t)(d + 3) * H_ + h, f32);
  }
  for (int d = 0; d < D_; d += 4) {
    a0 += ldin(x, b * D_ + d, f32)     * ldin(Wg, (size_t)(D_ + d) * H_ + h, f32);
    a1 += ldin(x, b * D_ + d + 1, f32) * ldin(Wg, (size_t)(D_ + d + 1) * H_ + h, f32);
    a2 += ldin(x, b * D_ + d + 2, f32) * ldin(Wg, (size_t)(D_ + d + 2) * H_ + h, f32);
    a3 += ldin(x, b * D_ + d + 3, f32) * ldin(Wg, (size_t)(D_ + d + 3) * H_ + h, f32);
  }
  float acc = (a0 + a1) + (a2 + a3);
  stout(dout, (size_t)b * H_ + h, fast_tanh(acc + ldin(bg, h, f32)), f32);
}

// ---------------------------------------------------------------------------
extern "C" void kernel_launch(void* const* d_in, const int* in_sizes, int n_in,
                              void* d_out, int out_size, void* d_ws, size_t ws_size,
                              hipStream_t stream) {
  const void* x    = d_in[0];
  const void* enc  = d_in[1];
  const void* fld  = d_in[2];
  const void* W_f  = d_in[3];
  const void* b_f  = d_in[4];
  const void* W_e  = d_in[5];
  const void* b_e  = d_in[6];
  const void* W_sf = d_in[7];
  const void* b_sf = d_in[8];
  const void* W_se = d_in[9];
  const void* b_se = d_in[10];
  const void* W_g  = d_in[11];
  const void* b_g  = d_in[12];

  float* ws    = (float*)d_ws;
  u32* flags   = (u32*)(ws + FLAGS_W);
  float* st_f  = ws + ST_F_W;
  float* st_x  = ws + ST_X_W;
  float* sc_e  = ws + SC_E_W;
  float* sc_f  = ws + SC_F_W;
  float* gam   = ws + GAM_W;
  float* ctx   = ws + CTX_W;
  u16* WpEH    = (u16*)(ws + WPEH_W);
  u16* WpEL    = (u16*)(ws + WPEL_W);
  u16* WpFH    = (u16*)(ws + WPFH_W);
  u16* WpFL    = (u16*)(ws + WPFL_W);
  u32* canary  = (u32*)(ws + CANARY_W);

  probe_kernel<<<1, 256, 0, stream>>>((const u16*)W_e, flags, canary);
  zero_kernel<<<32, 1024, 0, stream>>>(ctx, B_ * D_);
  state_kernel<<<256, 256, 0, stream>>>(x, W_sf, b_sf, W_se, b_se, st_f, st_x, flags);
  pack_w_split<<<128, 256, 0, stream>>>(W_e, WpEH, WpEL, 512, flags);
  pack_w_split<<<64, 256, 0, stream>>>(W_f, WpFH, WpFL, 256, flags);
  score_mfma_split<512><<<1024, 512, 0, stream>>>(enc, WpEH, WpEL, b_e, st_x, sc_e, flags);
  score_mfma_split<256><<<1024, 512, 0, stream>>>(fld, WpFH, WpFL, b_f, st_f, sc_f, flags);
  check_kernel<<<256, 256, 0, stream>>>(sc_e, sc_f, flags);
  softmax_kernel<<<64, 256, 0, stream>>>(sc_e, sc_f, gam, d_out, flags);
  ctx_kernel<<<1024, 256, 0, stream>>>(gam, enc, ctx, flags);
  out_kernel<<<128, 256, 0, stream>>>(ctx, x, W_g, b_g, d_out, flags);
  diag_kernel<<<1, 64, 0, stream>>>(flags, canary, d_out);
}

// Round 3
// 567.172 us; speedup vs baseline: 2.9342x; 1.1778x over previous
//
#include <hip/hip_runtime.h>

// Problem constants
#define B_ 64
#define S_ 1024
#define D_ 512
#define F_ 256
#define H_ 512

// ws word-offset layout (fp32 words) — identical 622,612-word footprint.
// Overlays (stream-ordered, no races):
//   WPEL (WpE-lo) = old sc_em/sc_fm region; consumed by score2_kernel.
//   WPFL (WpF-lo) = gammas region; consumed by score2_kernel BEFORE
//                   softmax overwrites it with gammas.
#define FLAGS_W  0
#define ST_F_W   16
#define ST_X_W   32784
#define SC_E_W   65552
#define SC_F_W   131088
#define WPEL_W   196624
#define WPFL_W   327696
#define GAM_W    327696
#define CTX_W    393232
#define WPEH_W   426000
#define WPFH_W   557072
#define CANARY_W 622608
// total: 622612 words = 2,490,448 bytes

typedef __attribute__((ext_vector_type(8))) short bf16x8;
typedef __attribute__((ext_vector_type(4))) short bf16x4;
typedef __attribute__((ext_vector_type(4))) float f32x4;
typedef unsigned short u16;
typedef unsigned int u32;

__device__ inline float bf2f(u16 u) {
  u32 i = ((u32)u) << 16;
  float f;
  __builtin_memcpy(&f, &i, 4);
  return f;
}
__device__ inline u16 f2bf(float f) {
  u32 i;
  __builtin_memcpy(&i, &f, 4);
  u32 r = i + 0x7fffu + ((i >> 16) & 1u);  // RNE
  return (u16)(r >> 16);
}
// Truncate-hi split: hi = top16(v), lo = RNE-bf16(v - hi). lo captures the
// truncation residual exactly to 2^-17 relative — same accuracy as RNE split,
// ~40% fewer VALU ops. In bf16-input mode lo == 0 exactly.
__device__ inline void split_bf(float v, u16& h, u16& l) {
  u32 i;
  __builtin_memcpy(&i, &v, 4);
  h = (u16)(i >> 16);
  u32 hb = i & 0xFFFF0000u;
  float hf;
  __builtin_memcpy(&hf, &hb, 4);
  l = f2bf(v - hf);
}
// Dual-mode input load: f32 flag selects fp32 or bf16 interpretation.
__device__ inline float ldin(const void* p, size_t i, int f32) {
  return f32 ? ((const float*)p)[i] : bf2f(((const u16*)p)[i]);
}
__device__ inline void stout(void* p, size_t i, float v, int f32) {
  if (f32) ((float*)p)[i] = v;
  else ((u16*)p)[i] = f2bf(v);
}
__device__ inline float fast_tanh(float x) {
  float cx = fminf(15.f, fmaxf(-15.f, x));
  float e = __expf(2.f * cx);
  return (e - 1.f) * __builtin_amdgcn_rcpf(e + 1.f);
}

// ---------------------------------------------------------------------------
// Fused: block 0 = dtype probe (8192 u16 samples of W_e) + flags/canary init;
// blocks 1..32 zero ctx.
__global__ void probe_zero(const u16* __restrict__ We, u32* __restrict__ flags,
                           u32* __restrict__ canary, float* __restrict__ ctx) {
  if (blockIdx.x != 0) {
    int i = (blockIdx.x - 1) * 1024 + threadIdx.x * 4;
    *(f32x4*)&ctx[i] = (f32x4){0.f, 0.f, 0.f, 0.f};
    return;
  }
  __shared__ u32 cnt;
  if (threadIdx.x == 0) cnt = 0;
  __syncthreads();
  u32 local = 0;
  for (int i = threadIdx.x; i < 8192; i += 256) {
    u32 e = (We[i] >> 7) & 0xFF;  // bf16 exponent field
    if (e >= 134) ++local;        // |v| >= 128: impossible for bf16 N(0,1)*0.044 data
  }
  atomicAdd(&cnt, local);
  __syncthreads();
  if (threadIdx.x == 0) {
    flags[0] = (cnt > 128) ? 1u : 0u;  // 1 => inputs are fp32 (~48% hit rate vs ~0)
    for (int i = 1; i < 16; ++i) flags[i] = 0;
    canary[0] = 0xC0DE0001u; canary[1] = 0xC0DE0002u;
    canary[2] = 0xC0DE0003u; canary[3] = 0xC0DE0004u;
  }
}

// ---------------------------------------------------------------------------
__global__ void state_kernel(const void* __restrict__ x,
                             const void* __restrict__ Wsf, const void* __restrict__ bsf,
                             const void* __restrict__ Wse, const void* __restrict__ bse,
                             float* __restrict__ st_f, float* __restrict__ st_x,
                             const u32* __restrict__ flags) {
  const int f32 = flags[0];
  int tid = blockIdx.x * 256 + threadIdx.x;
  int h = tid & 511, b = (tid >> 9) & 63, which = tid >> 15;
  const void* W = which ? Wse : Wsf;
  const void* bias = which ? bse : bsf;
  float a[8] = {};
  for (int d = 0; d < D_; d += 8) {
#pragma unroll
    for (int j = 0; j < 8; ++j)
      a[j] += ldin(x, b * D_ + d + j, f32) * ldin(W, (size_t)(d + j) * H_ + h, f32);
  }
  float acc = ((a[0] + a[1]) + (a[2] + a[3])) + ((a[4] + a[5]) + (a[6] + a[7]));
  float v = fast_tanh(acc + ldin(bias, h, f32));
  (which ? st_x : st_f)[b * H_ + h] = v;
}

// ---------------------------------------------------------------------------
// Fused W pack (W_e + W_f) with hi/lo bf16 split (dual-mode input).
// Tile (kc,nc): 32 k x 16 n; lane holds 8 k-values (k=(lane>>4)*8+j) of column
// nb = nc*16 + (lane&15) — matches the MFMA B-fragment layout.
__global__ void pack2_kernel(const void* __restrict__ We, const void* __restrict__ Wf,
                             u16* __restrict__ WpEH, u16* __restrict__ WpEL,
                             u16* __restrict__ WpFH, u16* __restrict__ WpFL,
                             const u32* __restrict__ flags) {
  const int f32 = flags[0];
  int bid = blockIdx.x;
  const void* W;
  u16 *WpH, *WpL;
  int K, tb;
  if (bid < 128) { W = We; WpH = WpEH; WpL = WpEL; K = 512; tb = bid; }
  else           { W = Wf; WpH = WpFH; WpL = WpFL; K = 256; tb = bid - 128; }
  int t = tb * 256 + threadIdx.x;
  int lane = t & 63, tile = t >> 6;  // grid sized so tile < (K>>5)*32
  int kc = tile >> 5, nc = tile & 31;
  int kb = kc * 32 + ((lane >> 4) << 3);
  int nb = nc * 16 + (lane & 15);
  u16 vh[8], vl[8];
#pragma unroll
  for (int j = 0; j < 8; ++j) {
    float v = ldin(W, (size_t)(kb + j) * H_ + nb, f32);
    split_bf(v, vh[j], vl[j]);
  }
  size_t off = ((size_t)tile << 9) + (size_t)lane * 8;
#pragma unroll
  for (int j = 0; j < 8; ++j) {
    WpH[off + j] = vh[j];
    WpL[off + j] = vl[j];
  }
}

// ---------------------------------------------------------------------------
// CONSUMED score path: split-bf16 3-pass MFMA (Ah*Wh + Al*Wh + Ah*Wl).
// Merged grid: blocks [0,1024) = enc/K=512 -> sc_e; [1024,2048) = fld/K=256 -> sc_f.
// T14 async-STAGE (A-tile global loads in flight across compute phase),
// register double-buffered B-fragments (one kc ahead, hides L2 latency),
// T5 setprio around the MFMA cluster.
__global__ void __launch_bounds__(512, 2) score2_kernel(
    const void* __restrict__ enc, const void* __restrict__ fld,
    const u16* __restrict__ WpEH, const u16* __restrict__ WpEL,
    const u16* __restrict__ WpFH, const u16* __restrict__ WpFL,
    const void* __restrict__ be, const void* __restrict__ bfp,
    const float* __restrict__ stx, const float* __restrict__ stf,
    float* __restrict__ sce, float* __restrict__ scf,
    const u32* __restrict__ flags) {
  constexpr int KP = 128, LDK = KP + 8;
  __shared__ __attribute__((aligned(16))) short AsH[64 * LDK];
  __shared__ __attribute__((aligned(16))) short AsL[64 * LDK];
  __shared__ float scw[8][64];
  const int f32 = flags[0];
  const int tid = threadIdx.x;
  int bid = blockIdx.x;
  const int sel = bid >> 10;
  bid &= 1023;
  const void* A    = sel ? fld : enc;
  const u16* WpH   = sel ? WpFH : WpEH;
  const u16* WpL   = sel ? WpFL : WpEL;
  const void* bias = sel ? bfp : be;
  const float* st  = sel ? stf : stx;
  float* score     = sel ? scf : sce;
  const int K = sel ? F_ : D_;
  const int NPH = K >> 7, NK = NPH * 4;

  const int m0 = bid * 64;
  const int b = m0 >> 10, s0 = m0 & 1023;
  const int lane = tid & 63, wave = tid >> 6;
  const int ml = lane & 15, q = lane >> 4;
  const int nb = wave * 4;
  const bf16x8* wph = (const bf16x8*)WpH;
  const bf16x8* wpl = (const bf16x8*)WpL;
  // Per-thread staging slice: 4 chunks of 4 elems; row (tid>>5)+16*it,
  // col-chunk (tid&31). Coalesced: lanes cover 512B-contiguous row segments.
  const int sr = tid >> 5, scc = tid & 31;
  f32x4 pre[4];   // fp32-mode prefetch
  bf16x4 preb[4]; // bf16-mode prefetch

#define ISSUE_LOADS(PH)                                                              \
  do {                                                                               \
    if (f32) {                                                                       \
      _Pragma("unroll") for (int it = 0; it < 4; ++it)                               \
          pre[it] = *(const f32x4*)((const float*)A +                                \
                                    (size_t)(m0 + sr + 16 * it) * K + (PH)*KP + scc * 4); \
    } else {                                                                         \
      _Pragma("unroll") for (int it = 0; it < 4; ++it)                               \
          preb[it] = *(const bf16x4*)((const u16*)A +                                \
                                      (size_t)(m0 + sr + 16 * it) * K + (PH)*KP + scc * 4); \
    }                                                                                \
  } while (0)

#define WRITE_STAGE()                                                                \
  do {                                                                               \
    _Pragma("unroll") for (int it = 0; it < 4; ++it) {                               \
      float v[4];                                                                    \
      if (f32) {                                                                     \
        v[0] = pre[it][0]; v[1] = pre[it][1]; v[2] = pre[it][2]; v[3] = pre[it][3];  \
      } else {                                                                       \
        v[0] = bf2f((u16)preb[it][0]); v[1] = bf2f((u16)preb[it][1]);                \
        v[2] = bf2f((u16)preb[it][2]); v[3] = bf2f((u16)preb[it][3]);                \
      }                                                                              \
      bf16x4 hv, lv;                                                                 \
      _Pragma("unroll") for (int j = 0; j < 4; ++j) {                                \
        u16 hh, ll;                                                                  \
        split_bf(v[j], hh, ll);                                                      \
        hv[j] = (short)hh;                                                           \
        lv[j] = (short)ll;                                                           \
      }                                                                              \
      *(bf16x4*)&AsH[(sr + 16 * it) * LDK + scc * 4] = hv;                           \
      *(bf16x4*)&AsL[(sr + 16 * it) * LDK + scc * 4] = lv;                           \
    }                                                                                \
  } while (0)

#define LOAD_B(DH, DL, KCG)                                                          \
  do {                                                                               \
    _Pragma("unroll") for (int ns = 0; ns < 4; ++ns) {                               \
      size_t widx = (size_t)((KCG)*32 + nb + ns) * 64 + lane;                        \
      DH[ns] = wph[widx];                                                            \
      DL[ns] = wpl[widx];                                                            \
    }                                                                                \
  } while (0)

  f32x4 acc[4][4] = {};
  bf16x8 bh[4], bl[4], bhn[4], bln[4];
  // Prologue: stage phase 0, prefetch B for kcg=0.
  ISSUE_LOADS(0);
  WRITE_STAGE();
  LOAD_B(bh, bl, 0);
  __syncthreads();
  for (int ph = 0; ph < NPH; ++ph) {
    if (ph + 1 < NPH) ISSUE_LOADS(ph + 1);  // A-tile in flight across compute phase
#pragma unroll
    for (int kc = 0; kc < KP / 32; ++kc) {
      const int kcg = ph * (KP / 32) + kc;
      const int kcn = (kcg + 1 < NK) ? (kcg + 1) : kcg;  // last prefetch harmless
      LOAD_B(bhn, bln, kcn);  // next-kc B-frags in flight under this kc's MFMA
      bf16x8 ah[4], al[4];
#pragma unroll
      for (int ms = 0; ms < 4; ++ms) {
        ah[ms] = *(const bf16x8*)&AsH[(ms * 16 + ml) * LDK + kc * 32 + q * 8];
        al[ms] = *(const bf16x8*)&AsL[(ms * 16 + ml) * LDK + kc * 32 + q * 8];
      }
      __builtin_amdgcn_s_setprio(1);
#pragma unroll
      for (int ms = 0; ms < 4; ++ms)
#pragma unroll
        for (int ns = 0; ns < 4; ++ns) {
          acc[ms][ns] = __builtin_amdgcn_mfma_f32_16x16x32_bf16(ah[ms], bh[ns], acc[ms][ns], 0, 0, 0);
          acc[ms][ns] = __builtin_amdgcn_mfma_f32_16x16x32_bf16(al[ms], bh[ns], acc[ms][ns], 0, 0, 0);
          acc[ms][ns] = __builtin_amdgcn_mfma_f32_16x16x32_bf16(ah[ms], bl[ns], acc[ms][ns], 0, 0, 0);
        }
      __builtin_amdgcn_s_setprio(0);
#pragma unroll
      for (int ns = 0; ns < 4; ++ns) { bh[ns] = bhn[ns]; bl[ns] = bln[ns]; }
    }
    if (ph + 1 < NPH) {
      __syncthreads();   // all reads of As done
      WRITE_STAGE();     // compiler inserts vmcnt before pre[] use
      __syncthreads();   // As ready for next phase
    }
  }
  // Epilogue: tanh + st-weighted reduce over h. C layout: col=lane&15,
  // row=(lane>>4)*4+reg (m89-verified mapping).
  float biasn[4], stn[4];
#pragma unroll
  for (int ns = 0; ns < 4; ++ns) {
    int n = (nb + ns) * 16 + ml;
    biasn[ns] = ldin(bias, n, f32);
    stn[ns] = st[b * H_ + n];
  }
#pragma unroll
  for (int ms = 0; ms < 4; ++ms) {
#pragma unroll
    for (int r = 0; r < 4; ++r) {
      float p = 0.f;
#pragma unroll
      for (int ns = 0; ns < 4; ++ns)
        p += fast_tanh(acc[ms][ns][r] + biasn[ns]) * stn[ns];
      p += __shfl_xor(p, 1);
      p += __shfl_xor(p, 2);
      p += __shfl_xor(p, 4);
      p += __shfl_xor(p, 8);
      if (ml == 0) scw[wave][ms * 16 + q * 4 + r] = p;
    }
  }
  __syncthreads();
  if (tid < 64) {
    float s = 0.f;
#pragma unroll
    for (int w = 0; w < 8; ++w) s += scw[w][tid];
    score[b * S_ + s0 + tid] = s;
  }
#undef ISSUE_LOADS
#undef WRITE_STAGE
#undef LOAD_B
}

// ---------------------------------------------------------------------------
__device__ inline float block_reduce_max(float v, float* red, int tid) {
#pragma unroll
  for (int off = 32; off >= 1; off >>= 1) v = fmaxf(v, __shfl_xor(v, off));
  if ((tid & 63) == 0) red[tid >> 6] = v;
  __syncthreads();
  v = fmaxf(fmaxf(red[0], red[1]), fmaxf(red[2], red[3]));
  __syncthreads();
  return v;
}
__device__ inline float block_reduce_sum(float v, float* red, int tid) {
#pragma unroll
  for (int off = 32; off >= 1; off >>= 1) v += __shfl_xor(v, off);
  if ((tid & 63) == 0) red[tid >> 6] = v;
  __syncthreads();
  v = red[0] + red[1] + red[2] + red[3];
  __syncthreads();
  return v;
}

// Softmax + fused NaN/magnitude guard (sets flags[4], consumed by out_kernel).
__global__ void softmax_kernel(const float* __restrict__ se, const float* __restrict__ sf,
                               float* __restrict__ gam, void* __restrict__ dout,
                               u32* __restrict__ flags) {
  __shared__ float red[4];
  const int f32 = flags[0];
  int b = blockIdx.x, t = threadIdx.x;
  float e[4], f[4];
#pragma unroll
  for (int i = 0; i < 4; ++i) {
    e[i] = se[b * S_ + t + 256 * i];
    f[i] = sf[b * S_ + t + 256 * i];
    if (!(fabsf(e[i]) < 1e4f) || !(fabsf(f[i]) < 1e4f)) flags[4] = 1;
  }
  float me = block_reduce_max(fmaxf(fmaxf(e[0], e[1]), fmaxf(e[2], e[3])), red, t);
  float mf = block_reduce_max(fmaxf(fmaxf(f[0], f[1]), fmaxf(f[2], f[3])), red, t);
  float sume = 0.f, sumf = 0.f;
#pragma unroll
  for (int i = 0; i < 4; ++i) {
    e[i] = __expf(e[i] - me);
    sume += e[i];
    f[i] = __expf(f[i] - mf);
    sumf += f[i];
  }
  sume = block_reduce_sum(sume, red, t);
  sumf = block_reduce_sum(sumf, red, t);
  float g[4], tot = 0.f;
#pragma unroll
  for (int i = 0; i < 4; ++i) {
    g[i] = (e[i] / sume) * (f[i] / sumf);
    tot += g[i];
  }
  tot = block_reduce_sum(tot, red, t);
  float scale = 1.f / (1e-6f + tot);
#pragma unroll
  for (int i = 0; i < 4; ++i) {
    int s = t + 256 * i;
    float gv = g[i] * scale;
    gam[b * S_ + s] = gv;
    stout(dout, (size_t)B_ * H_ + (size_t)s * B_ + b, gv, f32);  // gammas [S,B]
  }
}

// ---------------------------------------------------------------------------
__global__ void ctx_kernel(const float* __restrict__ gam, const void* __restrict__ enc,
                           float* __restrict__ ctx, const u32* __restrict__ flags) {
  const int f32 = flags[0];
  int b = blockIdx.x >> 4, sc = blockIdx.x & 15;
  int t = threadIdx.x, d0 = t * 2;
  float a0 = 0.f, a1 = 0.f;
#pragma unroll 4
  for (int s = sc * 64; s < sc * 64 + 64; ++s) {
    float g = gam[b * S_ + s];
    size_t base = ((size_t)(b * S_ + s)) * D_ + d0;
    a0 += g * ldin(enc, base, f32);
    a1 += g * ldin(enc, base + 1, f32);
  }
  atomicAdd(&ctx[b * D_ + d0], a0);
  atomicAdd(&ctx[b * D_ + d0 + 1], a1);
}

// ---------------------------------------------------------------------------
// Fused out + diag: thread (b=0,h=0) overrides out[0] with an error code on
// pipeline-poisoning faults (canary clobber, NaN scores).
__global__ void out_kernel(const float* __restrict__ ctx, const void* __restrict__ x,
                           const void* __restrict__ Wg, const void* __restrict__ bg,
                           void* __restrict__ dout, const u32* __restrict__ flags,
                           const u32* __restrict__ canary) {
  const int f32 = flags[0];
  int tid = blockIdx.x * 256 + threadIdx.x;
  int h = tid & 511, b = tid >> 9;
  float a0 = 0.f, a1 = 0.f, a2 = 0.f, a3 = 0.f;
  for (int d = 0; d < D_; d += 4) {
    a0 += ctx[b * D_ + d]     * ldin(Wg, (size_t)d * H_ + h, f32);
    a1 += ctx[b * D_ + d + 1] * ldin(Wg, (size_t)(d + 1) * H_ + h, f32);
    a2 += ctx[b * D_ + d + 2] * ldin(Wg, (size_t)(d + 2) * H_ + h, f32);
    a3 += ctx[b * D_ + d + 3] * ldin(Wg, (size_t)(d + 3) * H_ + h, f32);
  }
  for (int d = 0; d < D_; d += 4) {
    a0 += ldin(x, b * D_ + d, f32)     * ldin(Wg, (size_t)(D_ + d) * H_ + h, f32);
    a1 += ldin(x, b * D_ + d + 1, f32) * ldin(Wg, (size_t)(D_ + d + 1) * H_ + h, f32);
    a2 += ldin(x, b * D_ + d + 2, f32) * ldin(Wg, (size_t)(D_ + d + 2) * H_ + h, f32);
    a3 += ldin(x, b * D_ + d + 3, f32) * ldin(Wg, (size_t)(D_ + d + 3) * H_ + h, f32);
  }
  float acc = (a0 + a1) + (a2 + a3);
  float v = fast_tanh(acc + ldin(bg, h, f32));
  if (tid == 0) {
    u32 code = 0;
    if (canary[0] != 0xC0DE0001u || canary[1] != 0xC0DE0002u ||
        canary[2] != 0xC0DE0003u || canary[3] != 0xC0DE0004u) code += 32;
    if (flags[4]) code += 64;
    if (code) v = (float)code;
  }
  stout(dout, (size_t)b * H_ + h, v, f32);
}

// ---------------------------------------------------------------------------
extern "C" void kernel_launch(void* const* d_in, const int* in_sizes, int n_in,
                              void* d_out, int out_size, void* d_ws, size_t ws_size,
                              hipStream_t stream) {
  const void* x    = d_in[0];
  const void* enc  = d_in[1];
  const void* fld  = d_in[2];
  const void* W_f  = d_in[3];
  const void* b_f  = d_in[4];
  const void* W_e  = d_in[5];
  const void* b_e  = d_in[6];
  const void* W_sf = d_in[7];
  const void* b_sf = d_in[8];
  const void* W_se = d_in[9];
  const void* b_se = d_in[10];
  const void* W_g  = d_in[11];
  const void* b_g  = d_in[12];

  float* ws    = (float*)d_ws;
  u32* flags   = (u32*)(ws + FLAGS_W);
  float* st_f  = ws + ST_F_W;
  float* st_x  = ws + ST_X_W;
  float* sc_e  = ws + SC_E_W;
  float* sc_f  = ws + SC_F_W;
  float* gam   = ws + GAM_W;
  float* ctx   = ws + CTX_W;
  u16* WpEH    = (u16*)(ws + WPEH_W);
  u16* WpEL    = (u16*)(ws + WPEL_W);
  u16* WpFH    = (u16*)(ws + WPFH_W);
  u16* WpFL    = (u16*)(ws + WPFL_W);
  u32* canary  = (u32*)(ws + CANARY_W);

  probe_zero<<<33, 256, 0, stream>>>((const u16*)W_e, flags, canary, ctx);
  state_kernel<<<256, 256, 0, stream>>>(x, W_sf, b_sf, W_se, b_se, st_f, st_x, flags);
  pack2_kernel<<<192, 256, 0, stream>>>(W_e, W_f, WpEH, WpEL, WpFH, WpFL, flags);
  score2_kernel<<<2048, 512, 0, stream>>>(enc, fld, WpEH, WpEL, WpFH, WpFL,
                                          b_e, b_f, st_x, st_f, sc_e, sc_f, flags);
  softmax_kernel<<<64, 256, 0, stream>>>(sc_e, sc_f, gam, d_out, flags);
  ctx_kernel<<<1024, 256, 0, stream>>>(gam, enc, ctx, flags);
  out_kernel<<<128, 256, 0, stream>>>(ctx, x, W_g, b_g, d_out, flags, canary);
}

// Round 4
// 560.734 us; speedup vs baseline: 2.9679x; 1.0115x over previous
//
#include <hip/hip_runtime.h>

// Problem constants
#define B_ 64
#define S_ 1024
#define D_ 512
#define F_ 256
#define H_ 512

// ws word-offset layout (fp32 words) — identical 622,612-word footprint.
// Overlays (stream-ordered, no races):
//   WPEL (WpE-lo) = old sc_em/sc_fm region; consumed by score2_kernel.
//   WPFL (WpF-lo) = old gammas region (gammas now live only in ctx2's LDS).
#define FLAGS_W  0
#define ST_F_W   16
#define ST_X_W   32784
#define SC_E_W   65552
#define SC_F_W   131088
#define WPEL_W   196624
#define WPFL_W   327696
#define CTX_W    393232
#define WPEH_W   426000
#define WPFH_W   557072
#define CANARY_W 622608
// total: 622612 words = 2,490,448 bytes

typedef __attribute__((ext_vector_type(8))) short bf16x8;
typedef __attribute__((ext_vector_type(4))) short bf16x4;
typedef __attribute__((ext_vector_type(4))) float f32x4;
typedef unsigned short u16;
typedef unsigned int u32;

__device__ inline float bf2f(u16 u) {
  u32 i = ((u32)u) << 16;
  float f;
  __builtin_memcpy(&f, &i, 4);
  return f;
}
__device__ inline u16 f2bf(float f) {
  u32 i;
  __builtin_memcpy(&i, &f, 4);
  u32 r = i + 0x7fffu + ((i >> 16) & 1u);  // RNE
  return (u16)(r >> 16);
}
// Truncate-hi split: hi = top16(v), lo = RNE-bf16(v - hi). lo captures the
// truncation residual exactly to 2^-17 relative. In bf16-input mode lo == 0.
__device__ inline void split_bf(float v, u16& h, u16& l) {
  u32 i;
  __builtin_memcpy(&i, &v, 4);
  h = (u16)(i >> 16);
  u32 hb = i & 0xFFFF0000u;
  float hf;
  __builtin_memcpy(&hf, &hb, 4);
  l = f2bf(v - hf);
}
// Packed lo-convert: 2 f32 -> 1 u32 of 2 bf16 (RNE). No builtin on gfx950.
__device__ inline u32 cvt_pk_bf16(float a, float b) {
  u32 r;
  asm("v_cvt_pk_bf16_f32 %0, %1, %2" : "=v"(r) : "v"(a), "v"(b));
  return r;
}
// Dual-mode input load: f32 flag selects fp32 or bf16 interpretation.
__device__ inline float ldin(const void* p, size_t i, int f32) {
  return f32 ? ((const float*)p)[i] : bf2f(((const u16*)p)[i]);
}
__device__ inline void stout(void* p, size_t i, float v, int f32) {
  if (f32) ((float*)p)[i] = v;
  else ((u16*)p)[i] = f2bf(v);
}
__device__ inline float fast_tanh(float x) {
  float cx = fminf(15.f, fmaxf(-15.f, x));
  float e = __expf(2.f * cx);
  return (e - 1.f) * __builtin_amdgcn_rcpf(e + 1.f);
}

// ---------------------------------------------------------------------------
// Fused prep: every block derives the fp32 flag locally from the SAME 1024
// u16 samples of W_e (deterministic -> identical verdict, no cross-block dep).
// bid 0..31: zero ctx (bid 0 also publishes flags/canary for later kernels).
// bid 32..287: state GEMV+tanh. bid 288..479: W pack (hi/lo split).
__global__ void prep_kernel(const u16* __restrict__ We16,
                            const void* __restrict__ We, const void* __restrict__ Wf,
                            const void* __restrict__ x,
                            const void* __restrict__ Wsf, const void* __restrict__ bsf,
                            const void* __restrict__ Wse, const void* __restrict__ bse,
                            float* __restrict__ st_f, float* __restrict__ st_x,
                            u16* __restrict__ WpEH, u16* __restrict__ WpEL,
                            u16* __restrict__ WpFH, u16* __restrict__ WpFL,
                            u32* __restrict__ flags, u32* __restrict__ canary,
                            float* __restrict__ ctx) {
  __shared__ u32 cnt;
  if (threadIdx.x == 0) cnt = 0;
  __syncthreads();
  u32 local = 0;
  for (int i = threadIdx.x; i < 1024; i += 256) {
    u32 e = (We16[i] >> 7) & 0xFF;  // bf16 exponent field
    if (e >= 134) ++local;          // fp32 lower-halves hit ~48%; bf16 data ~0%
  }
  if (local) atomicAdd(&cnt, local);
  __syncthreads();
  const int f32 = cnt > 64;
  const int bid = blockIdx.x, t = threadIdx.x;

  if (bid < 32) {  // ---- zero ctx + (block 0) flags/canary
    int i = bid * 1024 + t * 4;
    *(f32x4*)&ctx[i] = (f32x4){0.f, 0.f, 0.f, 0.f};
    if (bid == 0 && t == 0) {
      flags[0] = (u32)f32;
      for (int i2 = 1; i2 < 16; ++i2) flags[i2] = 0;
      canary[0] = 0xC0DE0001u; canary[1] = 0xC0DE0002u;
      canary[2] = 0xC0DE0003u; canary[3] = 0xC0DE0004u;
    }
    return;
  }
  if (bid < 288) {  // ---- state: st = tanh(x @ W + b), two weights
    int tid = (bid - 32) * 256 + t;
    int h = tid & 511, b = (tid >> 9) & 63, which = tid >> 15;
    const void* W = which ? Wse : Wsf;
    const void* bias = which ? bse : bsf;
    float a[8] = {};
    for (int d = 0; d < D_; d += 8) {
#pragma unroll
      for (int j = 0; j < 8; ++j)
        a[j] += ldin(x, b * D_ + d + j, f32) * ldin(W, (size_t)(d + j) * H_ + h, f32);
    }
    float acc = ((a[0] + a[1]) + (a[2] + a[3])) + ((a[4] + a[5]) + (a[6] + a[7]));
    float v = fast_tanh(acc + ldin(bias, h, f32));
    (which ? st_x : st_f)[b * H_ + h] = v;
    return;
  }
  // ---- pack: tile (kc,nc) 32k x 16n; lane holds 8 k of column nb — matches
  // the MFMA B-fragment layout.
  int tb = bid - 288;
  const void* W;
  u16 *WpH, *WpL;
  int K;
  if (tb < 128) { W = We; WpH = WpEH; WpL = WpEL; K = 512; }
  else          { W = Wf; WpH = WpFH; WpL = WpFL; K = 256; tb -= 128; }
  int tg = tb * 256 + t;
  int lane = tg & 63, tile = tg >> 6;  // grid sized so tile < (K>>5)*32
  int kc = tile >> 5, nc = tile & 31;
  int kb = kc * 32 + ((lane >> 4) << 3);
  int nb = nc * 16 + (lane & 15);
  u16 vh[8], vl[8];
#pragma unroll
  for (int j = 0; j < 8; ++j) {
    float v = ldin(W, (size_t)(kb + j) * H_ + nb, f32);
    split_bf(v, vh[j], vl[j]);
  }
  size_t off = ((size_t)tile << 9) + (size_t)lane * 8;
#pragma unroll
  for (int j = 0; j < 8; ++j) {
    WpH[off + j] = vh[j];
    WpL[off + j] = vl[j];
  }
}

// ---------------------------------------------------------------------------
// CONSUMED score path: split-bf16 3-pass MFMA (Ah*Wh + Al*Wh + Ah*Wl).
// Merged grid: blocks [0,1024) = enc/K=512 -> sc_e; [1024,2048) = fld/K=256 -> sc_f.
// Double-buffered LDS, ONE barrier per phase: compute phase p from buf[p&1]
// while writing buf[p^1] (kc==2) and issuing loads for p+2 (kc==3).
// perm/cvt_pk packed split (~3x less staging VALU). B-frags reg-double-buffered.
__global__ void __launch_bounds__(512, 2) score2_kernel(
    const void* __restrict__ enc, const void* __restrict__ fld,
    const u16* __restrict__ WpEH, const u16* __restrict__ WpEL,
    const u16* __restrict__ WpFH, const u16* __restrict__ WpFL,
    const void* __restrict__ be, const void* __restrict__ bfp,
    const float* __restrict__ stx, const float* __restrict__ stf,
    float* __restrict__ sce, float* __restrict__ scf,
    const u32* __restrict__ flags) {
  constexpr int KP = 128, LDK = KP + 8;
  __shared__ __attribute__((aligned(16))) short AsH[2][64 * LDK];
  __shared__ __attribute__((aligned(16))) short AsL[2][64 * LDK];
  __shared__ float scw[8][64];
  const int f32 = flags[0];
  const int tid = threadIdx.x;
  int bid = blockIdx.x;
  const int sel = bid >> 10;
  bid &= 1023;
  const void* A    = sel ? fld : enc;
  const u16* WpH   = sel ? WpFH : WpEH;
  const u16* WpL   = sel ? WpFL : WpEL;
  const void* bias = sel ? bfp : be;
  const float* st  = sel ? stf : stx;
  float* score     = sel ? scf : sce;
  const int K = sel ? F_ : D_;
  const int NPH = K >> 7, NK = NPH * 4;

  const int m0 = bid * 64;
  const int b = m0 >> 10, s0 = m0 & 1023;
  const int lane = tid & 63, wave = tid >> 6;
  const int ml = lane & 15, q = lane >> 4;
  const int nb = wave * 4;
  const bf16x8* wph = (const bf16x8*)WpH;
  const bf16x8* wpl = (const bf16x8*)WpL;
  // Per-thread staging slice: 4 chunks of 4 elems; row (tid>>5)+16*it,
  // col-chunk (tid&31). Coalesced: lanes cover 512B-contiguous row segments.
  const int sr = tid >> 5, scc = tid & 31;
  f32x4 pre[4];   // fp32-mode prefetch
  bf16x4 preb[4]; // bf16-mode prefetch

#define ISSUE_LOADS(PH)                                                              \
  do {                                                                               \
    if (f32) {                                                                       \
      _Pragma("unroll") for (int it = 0; it < 4; ++it)                               \
          pre[it] = *(const f32x4*)((const float*)A +                                \
                                    (size_t)(m0 + sr + 16 * it) * K + (PH)*KP + scc * 4); \
    } else {                                                                         \
      _Pragma("unroll") for (int it = 0; it < 4; ++it)                               \
          preb[it] = *(const bf16x4*)((const u16*)A +                                \
                                      (size_t)(m0 + sr + 16 * it) * K + (PH)*KP + scc * 4); \
    }                                                                                \
  } while (0)

  // Packed split: v_perm packs 2 hi-halves (1 op); cvt_pk packs 2 lo's (1 op).
  // bf16 mode: iv = u16<<16 -> hi perm returns original u16s, lo == 0. Same path.
#define WRITE_STAGE(BUF)                                                             \
  do {                                                                               \
    _Pragma("unroll") for (int it = 0; it < 4; ++it) {                               \
      u32 iv[4];                                                                     \
      float vf[4];                                                                   \
      if (f32) {                                                                     \
        _Pragma("unroll") for (int j = 0; j < 4; ++j) {                              \
          vf[j] = pre[it][j];                                                        \
          __builtin_memcpy(&iv[j], &vf[j], 4);                                       \
        }                                                                            \
      } else {                                                                       \
        _Pragma("unroll") for (int j = 0; j < 4; ++j) {                              \
          iv[j] = ((u32)(u16)preb[it][j]) << 16;                                     \
          __builtin_memcpy(&vf[j], &iv[j], 4);                                       \
        }                                                                            \
      }                                                                              \
      u32 h01 = __builtin_amdgcn_perm(iv[1], iv[0], 0x07060302u);                    \
      u32 h23 = __builtin_amdgcn_perm(iv[3], iv[2], 0x07060302u);                    \
      float hf[4];                                                                   \
      _Pragma("unroll") for (int j = 0; j < 4; ++j) {                                \
        u32 hb = iv[j] & 0xFFFF0000u;                                                \
        __builtin_memcpy(&hf[j], &hb, 4);                                            \
      }                                                                              \
      u32 l01 = cvt_pk_bf16(vf[0] - hf[0], vf[1] - hf[1]);                           \
      u32 l23 = cvt_pk_bf16(vf[2] - hf[2], vf[3] - hf[3]);                           \
      u32* dH = (u32*)&AsH[BUF][(sr + 16 * it) * LDK + scc * 4];                     \
      u32* dL = (u32*)&AsL[BUF][(sr + 16 * it) * LDK + scc * 4];                     \
      dH[0] = h01; dH[1] = h23;                                                      \
      dL[0] = l01; dL[1] = l23;                                                      \
    }                                                                                \
  } while (0)

#define LOAD_B(DH, DL, KCG)                                                          \
  do {                                                                               \
    _Pragma("unroll") for (int ns = 0; ns < 4; ++ns) {                               \
      size_t widx = (size_t)((KCG)*32 + nb + ns) * 64 + lane;                        \
      DH[ns] = wph[widx];                                                            \
      DL[ns] = wpl[widx];                                                            \
    }                                                                                \
  } while (0)

  f32x4 acc[4][4] = {};
  bf16x8 bh[4], bl[4], bhn[4], bln[4];
  // Prologue: stage phase 0 into buf0, issue phase-1 loads, prefetch B kcg=0.
  ISSUE_LOADS(0);
  WRITE_STAGE(0);
  ISSUE_LOADS(1);
  LOAD_B(bh, bl, 0);
  __syncthreads();
  for (int ph = 0; ph < NPH; ++ph) {
    const int cur = ph & 1, nxt = cur ^ 1;
#pragma unroll
    for (int kc = 0; kc < 4; ++kc) {
      const int kcg = ph * 4 + kc;
      const int kcn = (kcg + 1 < NK) ? (kcg + 1) : kcg;  // last prefetch harmless
      LOAD_B(bhn, bln, kcn);  // next-kc B-frags in flight under this kc's MFMA
      bf16x8 ah[4], al[4];
#pragma unroll
      for (int ms = 0; ms < 4; ++ms) {
        ah[ms] = *(const bf16x8*)&AsH[cur][(ms * 16 + ml) * LDK + kc * 32 + q * 8];
        al[ms] = *(const bf16x8*)&AsL[cur][(ms * 16 + ml) * LDK + kc * 32 + q * 8];
      }
      if (kc == 2 && ph + 1 < NPH) WRITE_STAGE(nxt);   // overlap write w/ compute
      if (kc == 3 && ph + 2 < NPH) ISSUE_LOADS(ph + 2);  // pre[] free after write
      __builtin_amdgcn_s_setprio(1);
#pragma unroll
      for (int ms = 0; ms < 4; ++ms)
#pragma unroll
        for (int ns = 0; ns < 4; ++ns) {
          acc[ms][ns] = __builtin_amdgcn_mfma_f32_16x16x32_bf16(ah[ms], bh[ns], acc[ms][ns], 0, 0, 0);
          acc[ms][ns] = __builtin_amdgcn_mfma_f32_16x16x32_bf16(al[ms], bh[ns], acc[ms][ns], 0, 0, 0);
          acc[ms][ns] = __builtin_amdgcn_mfma_f32_16x16x32_bf16(ah[ms], bl[ns], acc[ms][ns], 0, 0, 0);
        }
      __builtin_amdgcn_s_setprio(0);
#pragma unroll
      for (int ns = 0; ns < 4; ++ns) { bh[ns] = bhn[ns]; bl[ns] = bln[ns]; }
    }
    __syncthreads();  // one barrier/phase: buf[nxt] writes done, buf[cur] reads done
  }
  // Epilogue: tanh + st-weighted reduce over h. C layout: col=lane&15,
  // row=(lane>>4)*4+reg (m89-verified mapping).
  float biasn[4], stn[4];
#pragma unroll
  for (int ns = 0; ns < 4; ++ns) {
    int n = (nb + ns) * 16 + ml;
    biasn[ns] = ldin(bias, n, f32);
    stn[ns] = st[b * H_ + n];
  }
#pragma unroll
  for (int ms = 0; ms < 4; ++ms) {
#pragma unroll
    for (int r = 0; r < 4; ++r) {
      float p = 0.f;
#pragma unroll
      for (int ns = 0; ns < 4; ++ns)
        p += fast_tanh(acc[ms][ns][r] + biasn[ns]) * stn[ns];
      p += __shfl_xor(p, 1);
      p += __shfl_xor(p, 2);
      p += __shfl_xor(p, 4);
      p += __shfl_xor(p, 8);
      if (ml == 0) scw[wave][ms * 16 + q * 4 + r] = p;
    }
  }
  __syncthreads();
  if (tid < 64) {
    float s = 0.f;
#pragma unroll
    for (int w = 0; w < 8; ++w) s += scw[w][tid];
    score[b * S_ + s0 + tid] = s;
  }
#undef ISSUE_LOADS
#undef WRITE_STAGE
#undef LOAD_B
}

// ---------------------------------------------------------------------------
__device__ inline float block_reduce_max(float v, float* red, int tid) {
#pragma unroll
  for (int off = 32; off >= 1; off >>= 1) v = fmaxf(v, __shfl_xor(v, off));
  if ((tid & 63) == 0) red[tid >> 6] = v;
  __syncthreads();
  v = fmaxf(fmaxf(red[0], red[1]), fmaxf(red[2], red[3]));
  __syncthreads();
  return v;
}
__device__ inline float block_reduce_sum(float v, float* red, int tid) {
#pragma unroll
  for (int off = 32; off >= 1; off >>= 1) v += __shfl_xor(v, off);
  if ((tid & 63) == 0) red[tid >> 6] = v;
  __syncthreads();
  v = red[0] + red[1] + red[2] + red[3];
  __syncthreads();
  return v;
}

// ---------------------------------------------------------------------------
// Fused softmax+ctx: each (b,sc) block redoes the cheap per-b softmax (L2-hot,
// runs in parallel; 16x redundant) and keeps gammas in LDS. sc==0 blocks write
// gammas to dout and the NaN guard. Then partial context accumulation.
__global__ void ctx2_kernel(const float* __restrict__ se, const float* __restrict__ sf,
                            const void* __restrict__ enc, float* __restrict__ ctx,
                            void* __restrict__ dout, u32* __restrict__ flags) {
  __shared__ float red[4];
  __shared__ float gl[S_];
  const int f32 = flags[0];
  int b = blockIdx.x >> 4, sc = blockIdx.x & 15;
  int t = threadIdx.x;
  float e[4], f[4];
  int bad = 0;
#pragma unroll
  for (int i = 0; i < 4; ++i) {
    e[i] = se[b * S_ + t + 256 * i];
    f[i] = sf[b * S_ + t + 256 * i];
    if (!(fabsf(e[i]) < 1e4f) || !(fabsf(f[i]) < 1e4f)) bad = 1;
  }
  if (bad && sc == 0) flags[4] = 1;
  float me = block_reduce_max(fmaxf(fmaxf(e[0], e[1]), fmaxf(e[2], e[3])), red, t);
  float mf = block_reduce_max(fmaxf(fmaxf(f[0], f[1]), fmaxf(f[2], f[3])), red, t);
  float sume = 0.f, sumf = 0.f;
#pragma unroll
  for (int i = 0; i < 4; ++i) {
    e[i] = __expf(e[i] - me);
    sume += e[i];
    f[i] = __expf(f[i] - mf);
    sumf += f[i];
  }
  sume = block_reduce_sum(sume, red, t);
  sumf = block_reduce_sum(sumf, red, t);
  float g[4], tot = 0.f;
#pragma unroll
  for (int i = 0; i < 4; ++i) {
    g[i] = (e[i] / sume) * (f[i] / sumf);
    tot += g[i];
  }
  tot = block_reduce_sum(tot, red, t);
  float scale = 1.f / (1e-6f + tot);
#pragma unroll
  for (int i = 0; i < 4; ++i) {
    int s = t + 256 * i;
    float gv = g[i] * scale;
    gl[s] = gv;
    if (sc == 0) stout(dout, (size_t)B_ * H_ + (size_t)s * B_ + b, gv, f32);  // gammas [S,B]
  }
  __syncthreads();
  int d0 = t * 2;
  float a0 = 0.f, a1 = 0.f;
#pragma unroll 4
  for (int s = sc * 64; s < sc * 64 + 64; ++s) {
    float gv = gl[s];
    size_t base = ((size_t)(b * S_ + s)) * D_ + d0;
    a0 += gv * ldin(enc, base, f32);
    a1 += gv * ldin(enc, base + 1, f32);
  }
  atomicAdd(&ctx[b * D_ + d0], a0);
  atomicAdd(&ctx[b * D_ + d0 + 1], a1);
}

// ---------------------------------------------------------------------------
// Fused out + diag: thread (b=0,h=0) overrides out[0] with an error code on
// pipeline-poisoning faults (canary clobber, NaN scores).
__global__ void out_kernel(const float* __restrict__ ctx, const void* __restrict__ x,
                           const void* __restrict__ Wg, const void* __restrict__ bg,
                           void* __restrict__ dout, const u32* __restrict__ flags,
                           const u32* __restrict__ canary) {
  const int f32 = flags[0];
  int tid = blockIdx.x * 256 + threadIdx.x;
  int h = tid & 511, b = tid >> 9;
  float a0 = 0.f, a1 = 0.f, a2 = 0.f, a3 = 0.f;
  for (int d = 0; d < D_; d += 4) {
    a0 += ctx[b * D_ + d]     * ldin(Wg, (size_t)d * H_ + h, f32);
    a1 += ctx[b * D_ + d + 1] * ldin(Wg, (size_t)(d + 1) * H_ + h, f32);
    a2 += ctx[b * D_ + d + 2] * ldin(Wg, (size_t)(d + 2) * H_ + h, f32);
    a3 += ctx[b * D_ + d + 3] * ldin(Wg, (size_t)(d + 3) * H_ + h, f32);
  }
  for (int d = 0; d < D_; d += 4) {
    a0 += ldin(x, b * D_ + d, f32)     * ldin(Wg, (size_t)(D_ + d) * H_ + h, f32);
    a1 += ldin(x, b * D_ + d + 1, f32) * ldin(Wg, (size_t)(D_ + d + 1) * H_ + h, f32);
    a2 += ldin(x, b * D_ + d + 2, f32) * ldin(Wg, (size_t)(D_ + d + 2) * H_ + h, f32);
    a3 += ldin(x, b * D_ + d + 3, f32) * ldin(Wg, (size_t)(D_ + d + 3) * H_ + h, f32);
  }
  float acc = (a0 + a1) + (a2 + a3);
  float v = fast_tanh(acc + ldin(bg, h, f32));
  if (tid == 0) {
    u32 code = 0;
    if (canary[0] != 0xC0DE0001u || canary[1] != 0xC0DE0002u ||
        canary[2] != 0xC0DE0003u || canary[3] != 0xC0DE0004u) code += 32;
    if (flags[4]) code += 64;
    if (code) v = (float)code;
  }
  stout(dout, (size_t)b * H_ + h, v, f32);
}

// ---------------------------------------------------------------------------
extern "C" void kernel_launch(void* const* d_in, const int* in_sizes, int n_in,
                              void* d_out, int out_size, void* d_ws, size_t ws_size,
                              hipStream_t stream) {
  const void* x    = d_in[0];
  const void* enc  = d_in[1];
  const void* fld  = d_in[2];
  const void* W_f  = d_in[3];
  const void* b_f  = d_in[4];
  const void* W_e  = d_in[5];
  const void* b_e  = d_in[6];
  const void* W_sf = d_in[7];
  const void* b_sf = d_in[8];
  const void* W_se = d_in[9];
  const void* b_se = d_in[10];
  const void* W_g  = d_in[11];
  const void* b_g  = d_in[12];

  float* ws    = (float*)d_ws;
  u32* flags   = (u32*)(ws + FLAGS_W);
  float* st_f  = ws + ST_F_W;
  float* st_x  = ws + ST_X_W;
  float* sc_e  = ws + SC_E_W;
  float* sc_f  = ws + SC_F_W;
  float* ctx   = ws + CTX_W;
  u16* WpEH    = (u16*)(ws + WPEH_W);
  u16* WpEL    = (u16*)(ws + WPEL_W);
  u16* WpFH    = (u16*)(ws + WPFH_W);
  u16* WpFL    = (u16*)(ws + WPFL_W);
  u32* canary  = (u32*)(ws + CANARY_W);

  prep_kernel<<<480, 256, 0, stream>>>((const u16*)W_e, W_e, W_f, x,
                                       W_sf, b_sf, W_se, b_se, st_f, st_x,
                                       WpEH, WpEL, WpFH, WpFL, flags, canary, ctx);
  score2_kernel<<<2048, 512, 0, stream>>>(enc, fld, WpEH, WpEL, WpFH, WpFL,
                                          b_e, b_f, st_x, st_f, sc_e, sc_f, flags);
  ctx2_kernel<<<1024, 256, 0, stream>>>(sc_e, sc_f, enc, ctx, d_out, flags);
  out_kernel<<<128, 256, 0, stream>>>(ctx, x, W_g, b_g, d_out, flags, canary);
}

// Round 5
// 455.298 us; speedup vs baseline: 3.6551x; 1.2316x over previous
//
#include <hip/hip_runtime.h>

// Problem constants
#define B_ 64
#define S_ 1024
#define D_ 512
#define F_ 256
#define H_ 512

// ws word-offset layout (fp32 words) — identical 622,612-word footprint.
#define FLAGS_W  0
#define ST_F_W   16
#define ST_X_W   32784
#define SC_E_W   65552
#define SC_F_W   131088
#define WPEL_W   196624
#define WPFL_W   327696
#define CTX_W    393232
#define WPEH_W   426000
#define WPFH_W   557072
#define CANARY_W 622608
// total: 622612 words = 2,490,448 bytes

typedef __attribute__((ext_vector_type(8))) short bf16x8;
typedef __attribute__((ext_vector_type(4))) short bf16x4;
typedef __attribute__((ext_vector_type(4))) float f32x4;
typedef __attribute__((ext_vector_type(2))) unsigned int u32x2;
typedef unsigned short u16;
typedef unsigned int u32;

__device__ inline float bf2f(u16 u) {
  u32 i = ((u32)u) << 16;
  float f;
  __builtin_memcpy(&f, &i, 4);
  return f;
}
__device__ inline u16 f2bf(float f) {
  u32 i;
  __builtin_memcpy(&i, &f, 4);
  u32 r = i + 0x7fffu + ((i >> 16) & 1u);  // RNE
  return (u16)(r >> 16);
}
// Truncate-hi split: hi = top16(v), lo = RNE-bf16(v - hi). lo captures the
// truncation residual exactly to 2^-17 relative. In bf16-input mode lo == 0.
__device__ inline void split_bf(float v, u16& h, u16& l) {
  u32 i;
  __builtin_memcpy(&i, &v, 4);
  h = (u16)(i >> 16);
  u32 hb = i & 0xFFFF0000u;
  float hf;
  __builtin_memcpy(&hf, &hb, 4);
  l = f2bf(v - hf);
}
// Packed lo-convert: 2 f32 -> 1 u32 of 2 bf16 (RNE). No builtin on gfx950.
__device__ inline u32 cvt_pk_bf16(float a, float b) {
  u32 r;
  asm("v_cvt_pk_bf16_f32 %0, %1, %2" : "=v"(r) : "v"(a), "v"(b));
  return r;
}
// Dual-mode input load (cold paths only; hot loops hoist the branch).
__device__ inline float ldin(const void* p, size_t i, int f32) {
  return f32 ? ((const float*)p)[i] : bf2f(((const u16*)p)[i]);
}
__device__ inline void stout(void* p, size_t i, float v, int f32) {
  if (f32) ((float*)p)[i] = v;
  else ((u16*)p)[i] = f2bf(v);
}
__device__ inline float fast_tanh(float x) {
  float cx = fminf(15.f, fmaxf(-15.f, x));
  float e = __expf(2.f * cx);
  return (e - 1.f) * __builtin_amdgcn_rcpf(e + 1.f);
}

// ---------------------------------------------------------------------------
// Fused prep: every block derives the fp32 flag locally from the SAME 1024
// u16 samples of W_e (deterministic -> identical verdict, no cross-block dep).
// bid 0..31: zero ctx (bid 0 publishes flags/canary). bid 32..287: state
// GEMV+tanh. bid 288..479: W pack (hi/lo split).
__global__ void prep_kernel(const u16* __restrict__ We16,
                            const void* __restrict__ We, const void* __restrict__ Wf,
                            const void* __restrict__ x,
                            const void* __restrict__ Wsf, const void* __restrict__ bsf,
                            const void* __restrict__ Wse, const void* __restrict__ bse,
                            float* __restrict__ st_f, float* __restrict__ st_x,
                            u16* __restrict__ WpEH, u16* __restrict__ WpEL,
                            u16* __restrict__ WpFH, u16* __restrict__ WpFL,
                            u32* __restrict__ flags, u32* __restrict__ canary,
                            float* __restrict__ ctx) {
  __shared__ u32 cnt;
  if (threadIdx.x == 0) cnt = 0;
  __syncthreads();
  u32 local = 0;
  for (int i = threadIdx.x; i < 1024; i += 256) {
    u32 e = (We16[i] >> 7) & 0xFF;  // bf16 exponent field
    if (e >= 134) ++local;          // fp32 lower-halves hit ~48%; bf16 data ~0%
  }
  if (local) atomicAdd(&cnt, local);
  __syncthreads();
  const int f32 = cnt > 64;
  const int bid = blockIdx.x, t = threadIdx.x;

  if (bid < 32) {  // ---- zero ctx + (block 0) flags/canary
    int i = bid * 1024 + t * 4;
    *(f32x4*)&ctx[i] = (f32x4){0.f, 0.f, 0.f, 0.f};
    if (bid == 0 && t == 0) {
      flags[0] = (u32)f32;
      for (int i2 = 1; i2 < 16; ++i2) flags[i2] = 0;
      canary[0] = 0xC0DE0001u; canary[1] = 0xC0DE0002u;
      canary[2] = 0xC0DE0003u; canary[3] = 0xC0DE0004u;
    }
    return;
  }
  if (bid < 288) {  // ---- state: st = tanh(x @ W + b), two weights
    int tid = (bid - 32) * 256 + t;
    int h = tid & 511, b = (tid >> 9) & 63, which = tid >> 15;
    float a[8] = {};
    if (f32) {
      const float* xp = (const float*)x + b * D_;
      const float* Wp = (const float*)(which ? Wse : Wsf) + h;
      for (int d = 0; d < D_; d += 8)
#pragma unroll
        for (int j = 0; j < 8; ++j)
          a[j] += xp[d + j] * Wp[(size_t)(d + j) * H_];
    } else {
      const u16* xp = (const u16*)x + b * D_;
      const u16* Wp = (const u16*)(which ? Wse : Wsf) + h;
      for (int d = 0; d < D_; d += 8)
#pragma unroll
        for (int j = 0; j < 8; ++j)
          a[j] += bf2f(xp[d + j]) * bf2f(Wp[(size_t)(d + j) * H_]);
    }
    float acc = ((a[0] + a[1]) + (a[2] + a[3])) + ((a[4] + a[5]) + (a[6] + a[7]));
    const void* bias = which ? bse : bsf;
    float v = fast_tanh(acc + ldin(bias, h, f32));
    (which ? st_x : st_f)[b * H_ + h] = v;
    return;
  }
  // ---- pack: tile (kc,nc) 32k x 16n; lane holds 8 k of column nb — matches
  // the MFMA B-fragment layout.
  int tb = bid - 288;
  const void* W;
  u16 *WpH, *WpL;
  if (tb < 128) { W = We; WpH = WpEH; WpL = WpEL; }
  else          { W = Wf; WpH = WpFH; WpL = WpFL; tb -= 128; }
  int tg = tb * 256 + t;
  int lane = tg & 63, tile = tg >> 6;
  int kc = tile >> 5, nc = tile & 31;
  int kb = kc * 32 + ((lane >> 4) << 3);
  int nb = nc * 16 + (lane & 15);
  float v[8];
  if (f32) {
    const float* Wp = (const float*)W + (size_t)kb * H_ + nb;
#pragma unroll
    for (int j = 0; j < 8; ++j) v[j] = Wp[(size_t)j * H_];
  } else {
    const u16* Wp = (const u16*)W + (size_t)kb * H_ + nb;
#pragma unroll
    for (int j = 0; j < 8; ++j) v[j] = bf2f(Wp[(size_t)j * H_]);
  }
  u16 vh[8], vl[8];
#pragma unroll
  for (int j = 0; j < 8; ++j) split_bf(v[j], vh[j], vl[j]);
  size_t off = ((size_t)tile << 9) + (size_t)lane * 8;
#pragma unroll
  for (int j = 0; j < 8; ++j) {
    WpH[off + j] = vh[j];
    WpL[off + j] = vl[j];
  }
}

// ---------------------------------------------------------------------------
// CONSUMED score path: split-bf16 3-pass MFMA (Ah*Wh + Al*Wh + Ah*Wl).
// Fully-unrolled K pipeline (template NPH): buffer parity, B-reg parity and
// ALL addressing are compile-time -> ds/global addrs = 1 VGPR + immediates,
// zero rotation movs. T14 async-STAGE + T5 setprio retained.
template <int K>
__device__ __forceinline__ void score_core(
    const void* __restrict__ A, const bf16x8* __restrict__ wph,
    const bf16x8* __restrict__ wpl, const void* __restrict__ bias,
    const float* __restrict__ st, float* __restrict__ score,
    int f32, int bid, int tid, char* AsHb, char* AsLb, float (*scw)[64]) {
  constexpr int KP = 128, LDK = KP + 8, NPH = K / KP, NK = NPH * 4;
  constexpr int BUFB = 64 * LDK * 2;  // bytes per LDS buffer

  const int m0 = bid * 64;
  const int b = m0 >> 10, s0 = m0 & 1023;
  const int lane = tid & 63, wave = tid >> 6;
  const int ml = lane & 15, q = lane >> 4;
  const int nb = wave * 4;
  // Staging slice: rows sr+16*it, col-chunk scc (4 elems).
  const int sr = tid >> 5, scc = tid & 31;
  // One-time per-thread byte offsets (all later addressing = imm folds).
  const u32 bofsB = ((u32)(nb * 64 + lane)) * 16u;          // B frag (ns imm)
  const u32 aoffB = ((u32)(ml * LDK + q * 8)) * 2u;         // A ds_read
  const u32 woffB = ((u32)(sr * LDK + scc * 4)) * 2u;       // staging ds_write
  f32x4 pre[4];
  bf16x4 preb[4];

#define ISSUE_LOADS(PH)                                                              \
  do {                                                                               \
    if (f32) {                                                                       \
      _Pragma("unroll") for (int it = 0; it < 4; ++it)                               \
          pre[it] = *(const f32x4*)((const float*)A +                                \
                                    (size_t)(m0 + sr + 16 * it) * K + (PH)*KP + scc * 4); \
    } else {                                                                         \
      _Pragma("unroll") for (int it = 0; it < 4; ++it)                               \
          preb[it] = *(const bf16x4*)((const u16*)A +                                \
                                      (size_t)(m0 + sr + 16 * it) * K + (PH)*KP + scc * 4); \
    }                                                                                \
  } while (0)

  // Packed split: v_perm packs 2 hi (1 op); cvt_pk packs 2 lo (1 op). b64 stores.
#define WRITE_STAGE(BUF)                                                             \
  do {                                                                               \
    _Pragma("unroll") for (int it = 0; it < 4; ++it) {                               \
      u32 iv[4];                                                                     \
      float vf[4];                                                                   \
      if (f32) {                                                                     \
        _Pragma("unroll") for (int j = 0; j < 4; ++j) {                              \
          vf[j] = pre[it][j];                                                        \
          __builtin_memcpy(&iv[j], &vf[j], 4);                                       \
        }                                                                            \
      } else {                                                                       \
        _Pragma("unroll") for (int j = 0; j < 4; ++j) {                              \
          iv[j] = ((u32)(u16)preb[it][j]) << 16;                                     \
          __builtin_memcpy(&vf[j], &iv[j], 4);                                       \
        }                                                                            \
      }                                                                              \
      u32 h01 = __builtin_amdgcn_perm(iv[1], iv[0], 0x07060302u);                    \
      u32 h23 = __builtin_amdgcn_perm(iv[3], iv[2], 0x07060302u);                    \
      float hf[4];                                                                   \
      _Pragma("unroll") for (int j = 0; j < 4; ++j) {                                \
        u32 hb = iv[j] & 0xFFFF0000u;                                                \
        __builtin_memcpy(&hf[j], &hb, 4);                                            \
      }                                                                              \
      u32x2 hv = {h01, h23};                                                         \
      u32x2 lv = {cvt_pk_bf16(vf[0] - hf[0], vf[1] - hf[1]),                         \
                  cvt_pk_bf16(vf[2] - hf[2], vf[3] - hf[3])};                        \
      *(u32x2*)(AsHb + (BUF)*BUFB + it * 4352 + woffB) = hv;                         \
      *(u32x2*)(AsLb + (BUF)*BUFB + it * 4352 + woffB) = lv;                         \
    }                                                                                \
  } while (0)

#define LOAD_B(P, KCG)                                                               \
  do {                                                                               \
    const char* hp_ = (const char*)(wph + (size_t)(KCG)*2048) + bofsB;               \
    const char* lp_ = (const char*)(wpl + (size_t)(KCG)*2048) + bofsB;               \
    _Pragma("unroll") for (int ns = 0; ns < 4; ++ns) {                               \
      bhp[P][ns] = *(const bf16x8*)(hp_ + ns * 1024);                                \
      blp[P][ns] = *(const bf16x8*)(lp_ + ns * 1024);                                \
    }                                                                                \
  } while (0)

  f32x4 acc[4][4] = {};
  bf16x8 bhp[2][4], blp[2][4];
  // Prologue: stage phase 0 into buf0, issue phase-1 loads, prefetch B kcg=0.
  ISSUE_LOADS(0);
  WRITE_STAGE(0);
  ISSUE_LOADS(1);
  LOAD_B(0, 0);
  __syncthreads();
#pragma unroll
  for (int ph = 0; ph < NPH; ++ph) {
    const int cur = ph & 1;  // literal under full unroll
#pragma unroll
    for (int kc = 0; kc < 4; ++kc) {
      const int kcg = ph * 4 + kc;
      const int use = kcg & 1, nxp = use ^ 1;
      const int kcn = (kcg + 1 < NK) ? (kcg + 1) : kcg;  // dead-load clamp
      LOAD_B(nxp, kcn);  // next-kc B frags in flight under this kc's MFMA
      bf16x8 ah[4], al[4];
#pragma unroll
      for (int ms = 0; ms < 4; ++ms) {
        ah[ms] = *(const bf16x8*)(AsHb + cur * BUFB + ms * 4352 + kc * 64 + aoffB);
        al[ms] = *(const bf16x8*)(AsLb + cur * BUFB + ms * 4352 + kc * 64 + aoffB);
      }
      if (kc == 2 && ph + 1 < NPH) WRITE_STAGE(cur ^ 1);   // overlap w/ compute
      if (kc == 3 && ph + 2 < NPH) ISSUE_LOADS(ph + 2);    // pre[] free after write
      __builtin_amdgcn_s_setprio(1);
#pragma unroll
      for (int ms = 0; ms < 4; ++ms)
#pragma unroll
        for (int ns = 0; ns < 4; ++ns) {
          acc[ms][ns] = __builtin_amdgcn_mfma_f32_16x16x32_bf16(ah[ms], bhp[use][ns], acc[ms][ns], 0, 0, 0);
          acc[ms][ns] = __builtin_amdgcn_mfma_f32_16x16x32_bf16(al[ms], bhp[use][ns], acc[ms][ns], 0, 0, 0);
          acc[ms][ns] = __builtin_amdgcn_mfma_f32_16x16x32_bf16(ah[ms], blp[use][ns], acc[ms][ns], 0, 0, 0);
        }
      __builtin_amdgcn_s_setprio(0);
    }
    __syncthreads();  // buf[cur^1] writes done, buf[cur] reads done
  }
  // Epilogue: tanh + st-weighted reduce over h. C layout: col=lane&15,
  // row=(lane>>4)*4+reg (m89-verified mapping).
  float biasn[4], stn[4];
#pragma unroll
  for (int ns = 0; ns < 4; ++ns) {
    int n = (nb + ns) * 16 + ml;
    biasn[ns] = ldin(bias, n, f32);
    stn[ns] = st[b * H_ + n];
  }
#pragma unroll
  for (int ms = 0; ms < 4; ++ms) {
#pragma unroll
    for (int r = 0; r < 4; ++r) {
      float p = 0.f;
#pragma unroll
      for (int ns = 0; ns < 4; ++ns)
        p += fast_tanh(acc[ms][ns][r] + biasn[ns]) * stn[ns];
      p += __shfl_xor(p, 1);
      p += __shfl_xor(p, 2);
      p += __shfl_xor(p, 4);
      p += __shfl_xor(p, 8);
      if (ml == 0) scw[wave][ms * 16 + q * 4 + r] = p;
    }
  }
  __syncthreads();
  if (tid < 64) {
    float s = 0.f;
#pragma unroll
    for (int w = 0; w < 8; ++w) s += scw[w][tid];
    score[b * S_ + s0 + tid] = s;
  }
#undef ISSUE_LOADS
#undef WRITE_STAGE
#undef LOAD_B
}

__global__ void __launch_bounds__(512, 2) score2_kernel(
    const void* __restrict__ enc, const void* __restrict__ fld,
    const u16* __restrict__ WpEH, const u16* __restrict__ WpEL,
    const u16* __restrict__ WpFH, const u16* __restrict__ WpFL,
    const void* __restrict__ be, const void* __restrict__ bfp,
    const float* __restrict__ stx, const float* __restrict__ stf,
    float* __restrict__ sce, float* __restrict__ scf,
    const u32* __restrict__ flags) {
  constexpr int LDK = 136;
  __shared__ __attribute__((aligned(16))) short AsH[2][64 * LDK];
  __shared__ __attribute__((aligned(16))) short AsL[2][64 * LDK];
  __shared__ float scw[8][64];
  const int f32 = flags[0];
  const int tid = threadIdx.x;
  int bid = blockIdx.x;
  if (bid < 1024) {
    score_core<512>(enc, (const bf16x8*)WpEH, (const bf16x8*)WpEL, be, stx, sce,
                    f32, bid, tid, (char*)AsH, (char*)AsL, scw);
  } else {
    score_core<256>(fld, (const bf16x8*)WpFH, (const bf16x8*)WpFL, bfp, stf, scf,
                    f32, bid - 1024, tid, (char*)AsH, (char*)AsL, scw);
  }
}

// ---------------------------------------------------------------------------
__device__ inline float block_reduce_max(float v, float* red, int tid) {
#pragma unroll
  for (int off = 32; off >= 1; off >>= 1) v = fmaxf(v, __shfl_xor(v, off));
  if ((tid & 63) == 0) red[tid >> 6] = v;
  __syncthreads();
  v = fmaxf(fmaxf(red[0], red[1]), fmaxf(red[2], red[3]));
  __syncthreads();
  return v;
}
__device__ inline float block_reduce_sum(float v, float* red, int tid) {
#pragma unroll
  for (int off = 32; off >= 1; off >>= 1) v += __shfl_xor(v, off);
  if ((tid & 63) == 0) red[tid >> 6] = v;
  __syncthreads();
  v = red[0] + red[1] + red[2] + red[3];
  __syncthreads();
  return v;
}

// ---------------------------------------------------------------------------
// Fused softmax+ctx: each (b,sc) block redoes the cheap per-b softmax (L2-hot,
// 16x redundant, parallel) and keeps gammas in LDS. sc==0 blocks write gammas
// to dout + NaN guard. Then partial context accumulation.
__global__ void ctx2_kernel(const float* __restrict__ se, const float* __restrict__ sf,
                            const void* __restrict__ enc, float* __restrict__ ctx,
                            void* __restrict__ dout, u32* __restrict__ flags) {
  __shared__ float red[4];
  __shared__ float gl[S_];
  const int f32 = flags[0];
  int b = blockIdx.x >> 4, sc = blockIdx.x & 15;
  int t = threadIdx.x;
  float e[4], f[4];
  int bad = 0;
#pragma unroll
  for (int i = 0; i < 4; ++i) {
    e[i] = se[b * S_ + t + 256 * i];
    f[i] = sf[b * S_ + t + 256 * i];
    if (!(fabsf(e[i]) < 1e4f) || !(fabsf(f[i]) < 1e4f)) bad = 1;
  }
  if (bad && sc == 0) flags[4] = 1;
  float me = block_reduce_max(fmaxf(fmaxf(e[0], e[1]), fmaxf(e[2], e[3])), red, t);
  float mf = block_reduce_max(fmaxf(fmaxf(f[0], f[1]), fmaxf(f[2], f[3])), red, t);
  float sume = 0.f, sumf = 0.f;
#pragma unroll
  for (int i = 0; i < 4; ++i) {
    e[i] = __expf(e[i] - me);
    sume += e[i];
    f[i] = __expf(f[i] - mf);
    sumf += f[i];
  }
  sume = block_reduce_sum(sume, red, t);
  sumf = block_reduce_sum(sumf, red, t);
  float g[4], tot = 0.f;
#pragma unroll
  for (int i = 0; i < 4; ++i) {
    g[i] = (e[i] / sume) * (f[i] / sumf);
    tot += g[i];
  }
  tot = block_reduce_sum(tot, red, t);
  float scale = 1.f / (1e-6f + tot);
#pragma unroll
  for (int i = 0; i < 4; ++i) {
    int s = t + 256 * i;
    float gv = g[i] * scale;
    gl[s] = gv;
    if (sc == 0) stout(dout, (size_t)B_ * H_ + (size_t)s * B_ + b, gv, f32);  // gammas [S,B]
  }
  __syncthreads();
  int d0 = t * 2;
  float a0 = 0.f, a1 = 0.f;
  if (f32) {
    const float* ep = (const float*)enc + ((size_t)(b * S_ + sc * 64)) * D_ + d0;
    const float* glp = &gl[sc * 64];
#pragma unroll 4
    for (int s = 0; s < 64; ++s) {
      float gv = glp[s];
      a0 += gv * ep[0];
      a1 += gv * ep[1];
      ep += D_;
    }
  } else {
    const u16* ep = (const u16*)enc + ((size_t)(b * S_ + sc * 64)) * D_ + d0;
    const float* glp = &gl[sc * 64];
#pragma unroll 4
    for (int s = 0; s < 64; ++s) {
      float gv = glp[s];
      a0 += gv * bf2f(ep[0]);
      a1 += gv * bf2f(ep[1]);
      ep += D_;
    }
  }
  atomicAdd(&ctx[b * D_ + d0], a0);
  atomicAdd(&ctx[b * D_ + d0 + 1], a1);
}

// ---------------------------------------------------------------------------
// Fused out + diag: thread (b=0,h=0) overrides out[0] with an error code on
// pipeline-poisoning faults (canary clobber, NaN scores).
__global__ void out_kernel(const float* __restrict__ ctx, const void* __restrict__ x,
                           const void* __restrict__ Wg, const void* __restrict__ bg,
                           void* __restrict__ dout, const u32* __restrict__ flags,
                           const u32* __restrict__ canary) {
  const int f32 = flags[0];
  int tid = blockIdx.x * 256 + threadIdx.x;
  int h = tid & 511, b = tid >> 9;
  const float* cp = ctx + b * D_;
  float a0 = 0.f, a1 = 0.f, a2 = 0.f, a3 = 0.f;
  if (f32) {
    const float* Wgp = (const float*)Wg + h;
    const float* xp = (const float*)x + b * D_;
    for (int d = 0; d < D_; d += 4) {
      a0 += cp[d]     * Wgp[(size_t)d * H_];
      a1 += cp[d + 1] * Wgp[(size_t)(d + 1) * H_];
      a2 += cp[d + 2] * Wgp[(size_t)(d + 2) * H_];
      a3 += cp[d + 3] * Wgp[(size_t)(d + 3) * H_];
    }
    const float* Wgx = Wgp + (size_t)D_ * H_;
    for (int d = 0; d < D_; d += 4) {
      a0 += xp[d]     * Wgx[(size_t)d * H_];
      a1 += xp[d + 1] * Wgx[(size_t)(d + 1) * H_];
      a2 += xp[d + 2] * Wgx[(size_t)(d + 2) * H_];
      a3 += xp[d + 3] * Wgx[(size_t)(d + 3) * H_];
    }
  } else {
    const u16* Wgp = (const u16*)Wg + h;
    const u16* xp = (const u16*)x + b * D_;
    for (int d = 0; d < D_; d += 4) {
      a0 += cp[d]     * bf2f(Wgp[(size_t)d * H_]);
      a1 += cp[d + 1] * bf2f(Wgp[(size_t)(d + 1) * H_]);
      a2 += cp[d + 2] * bf2f(Wgp[(size_t)(d + 2) * H_]);
      a3 += cp[d + 3] * bf2f(Wgp[(size_t)(d + 3) * H_]);
    }
    const u16* Wgx = Wgp + (size_t)D_ * H_;
    for (int d = 0; d < D_; d += 4) {
      a0 += bf2f(xp[d])     * bf2f(Wgx[(size_t)d * H_]);
      a1 += bf2f(xp[d + 1]) * bf2f(Wgx[(size_t)(d + 1) * H_]);
      a2 += bf2f(xp[d + 2]) * bf2f(Wgx[(size_t)(d + 2) * H_]);
      a3 += bf2f(xp[d + 3]) * bf2f(Wgx[(size_t)(d + 3) * H_]);
    }
  }
  float acc = (a0 + a1) + (a2 + a3);
  float v = fast_tanh(acc + ldin(bg, h, f32));
  if (tid == 0) {
    u32 code = 0;
    if (canary[0] != 0xC0DE0001u || canary[1] != 0xC0DE0002u ||
        canary[2] != 0xC0DE0003u || canary[3] != 0xC0DE0004u) code += 32;
    if (flags[4]) code += 64;
    if (code) v = (float)code;
  }
  stout(dout, (size_t)b * H_ + h, v, f32);
}

// ---------------------------------------------------------------------------
extern "C" void kernel_launch(void* const* d_in, const int* in_sizes, int n_in,
                              void* d_out, int out_size, void* d_ws, size_t ws_size,
                              hipStream_t stream) {
  const void* x    = d_in[0];
  const void* enc  = d_in[1];
  const void* fld  = d_in[2];
  const void* W_f  = d_in[3];
  const void* b_f  = d_in[4];
  const void* W_e  = d_in[5];
  const void* b_e  = d_in[6];
  const void* W_sf = d_in[7];
  const void* b_sf = d_in[8];
  const void* W_se = d_in[9];
  const void* b_se = d_in[10];
  const void* W_g  = d_in[11];
  const void* b_g  = d_in[12];

  float* ws    = (float*)d_ws;
  u32* flags   = (u32*)(ws + FLAGS_W);
  float* st_f  = ws + ST_F_W;
  float* st_x  = ws + ST_X_W;
  float* sc_e  = ws + SC_E_W;
  float* sc_f  = ws + SC_F_W;
  float* ctx   = ws + CTX_W;
  u16* WpEH    = (u16*)(ws + WPEH_W);
  u16* WpEL    = (u16*)(ws + WPEL_W);
  u16* WpFH    = (u16*)(ws + WPFH_W);
  u16* WpFL    = (u16*)(ws + WPFL_W);
  u32* canary  = (u32*)(ws + CANARY_W);

  prep_kernel<<<480, 256, 0, stream>>>((const u16*)W_e, W_e, W_f, x,
                                       W_sf, b_sf, W_se, b_se, st_f, st_x,
                                       WpEH, WpEL, WpFH, WpFL, flags, canary, ctx);
  score2_kernel<<<2048, 512, 0, stream>>>(enc, fld, WpEH, WpEL, WpFH, WpFL,
                                          b_e, b_f, st_x, st_f, sc_e, sc_f, flags);
  ctx2_kernel<<<1024, 256, 0, stream>>>(sc_e, sc_f, enc, ctx, d_out, flags);
  out_kernel<<<128, 256, 0, stream>>>(ctx, x, W_g, b_g, d_out, flags, canary);
}